// Round 5
// baseline (1970.684 us; speedup 1.0000x reference)
//
#include <hip/hip_runtime.h>
#include <hip/hip_bf16.h>

typedef __attribute__((ext_vector_type(8))) __bf16 bf16x8;
typedef __attribute__((ext_vector_type(4))) float f32x4;
typedef __hip_bfloat16 bf16;

#define DEV __device__ __forceinline__

constexpr int TT = 2048;      // B*S tokens
constexpr int NSLOT = 16384;  // TT * TOPK(8)

DEV void gl_lds16(const void* g, void* l) {
  __builtin_amdgcn_global_load_lds((const __attribute__((address_space(1))) unsigned int*)g,
                                   (__attribute__((address_space(3))) unsigned int*)l, 16, 0, 0);
}

DEV bf16 cvt(float v) { return __float2bfloat16(v); }

// ---------------- transpose + convert: dst[c][r] = src[r][c] split hi/lo, rows padded to Cpad (zero fill)
template <bool SPLIT>
__global__ __launch_bounds__(256) void transpose_cvt(const float* __restrict__ src, bf16* __restrict__ dst,
                                                     int R, int C, int Cpad) {
  int e = blockIdx.z;  // SPLIT calls always use gridDim.z == 1
  src += (size_t)e * R * C;
  dst += (size_t)e * Cpad * R;
  size_t pl = (size_t)Cpad * R;  // lo plane offset (elements)
  __shared__ float t[32][33];
  int c0 = blockIdx.x * 32, r0 = blockIdx.y * 32;
  int tx = threadIdx.x & 31, ty = threadIdx.x >> 5;
#pragma unroll
  for (int i = 0; i < 4; ++i) {
    int r = ty + i * 8;
    int cc = c0 + tx;
    float v = (cc < C) ? src[(size_t)(r0 + r) * C + cc] : 0.f;
    t[r][tx] = v;
  }
  __syncthreads();
#pragma unroll
  for (int i = 0; i < 4; ++i) {
    int c = ty + i * 8;
    float v = t[tx][c];
    size_t idx = (size_t)(c0 + c) * R + (r0 + tx);
    bf16 hi = cvt(v);
    dst[idx] = hi;
    if (SPLIT) dst[pl + idx] = cvt(v - (float)hi);
  }
}

// ---------------- RMSNorm: dst = src*rsqrt(mean(src^2)+eps)*w, optional hi/lo split output
template <bool SPLIT>
__global__ __launch_bounds__(256) void rms_k(const float* __restrict__ src, int sst, int C,
                                             const float* __restrict__ wgt, bf16* __restrict__ dst,
                                             size_t dstPl) {
  int t = blockIdx.x;
  const float* sp = src + (size_t)t * sst;
  bf16* dp = dst + (size_t)t * C;
  int n4 = C >> 2;
  float ss = 0.f;
  for (int i = threadIdx.x; i < n4; i += 256) {
    float4 v = ((const float4*)sp)[i];
    ss += v.x * v.x + v.y * v.y + v.z * v.z + v.w * v.w;
  }
#pragma unroll
  for (int d = 1; d < 64; d <<= 1) ss += __shfl_xor(ss, d, 64);
  __shared__ float part[4];
  if ((threadIdx.x & 63) == 0) part[threadIdx.x >> 6] = ss;
  __syncthreads();
  float rinv = rsqrtf((part[0] + part[1] + part[2] + part[3]) / (float)C + 1e-6f);
  for (int i = threadIdx.x; i < n4; i += 256) {
    float4 v = ((const float4*)sp)[i];
    float4 g = ((const float4*)wgt)[i];
    float y[4] = {v.x * rinv * g.x, v.y * rinv * g.y, v.z * rinv * g.z, v.w * rinv * g.w};
    union { bf16 h[4]; short4 s; } uh, ul;
#pragma unroll
    for (int j = 0; j < 4; ++j) {
      bf16 hi = cvt(y[j]);
      uh.h[j] = hi;
      ul.h[j] = cvt(y[j] - (float)hi);
    }
    ((short4*)dp)[i] = uh.s;
    if (SPLIT) ((short4*)(dp + dstPl))[i] = ul.s;
  }
}

// ---------------- generic 128x128 bf16 GEMM, C = A[M,K] * WT[N,K]^T, optional split-bf16 precision
enum { E_F32 = 0, E_ADDSRC = 1, E_ADDINTO = 2, E_SPLIT = 3, E_ATOMIC = 4 };

template <int EPI, bool EXPERT, bool SPLIT>
__global__ __launch_bounds__(256, 2)
void gemm128(const bf16* __restrict__ A, int lda, size_t aPl,
             const bf16* __restrict__ WT, size_t bPl, size_t wtsE, int K,
             void* __restrict__ Cout, size_t cPl, const float* __restrict__ SRC,
             int M, int N, int ldc,
             const int* __restrict__ cnt, const int* __restrict__ offs,
             const float* __restrict__ rowscale, const int* __restrict__ tok_of) {
  int e = EXPERT ? blockIdx.z : 0;
  int Mloc = EXPERT ? cnt[e] : M;
  int m0 = blockIdx.x * 128;
  if (EXPERT && m0 >= Mloc) return;
  int rowbase = EXPERT ? offs[e] : 0;
  const bf16* Ae = A + (size_t)rowbase * lda;
  const bf16* We = WT + (EXPERT ? (size_t)e * wtsE : 0);
  int n0 = blockIdx.y * 128;

  __shared__ __align__(16) bf16 Ab[(SPLIT ? 2 : 1) * 128 * 64];
  __shared__ __align__(16) bf16 Bb[(SPLIT ? 2 : 1) * 128 * 64];

  int tid = threadIdx.x, w = tid >> 6, l = tid & 63;
  int wr = w >> 1, wc = w & 1;
  int fe = w * 512 + l * 8, sr = fe >> 6, sk = fe & 63;

  f32x4 acc[4][4];
#pragma unroll
  for (int i = 0; i < 4; ++i)
#pragma unroll
    for (int j = 0; j < 4; ++j) acc[i][j] = (f32x4){0.f, 0.f, 0.f, 0.f};

  for (int k0 = 0; k0 < K; k0 += 64) {
    __syncthreads();
#pragma unroll
    for (int c = 0; c < 4; ++c) {
      int r = c * 32 + sr;
      gl_lds16(Ae + (size_t)(m0 + r) * lda + (k0 + sk), &Ab[c * 2048 + w * 512]);
      gl_lds16(We + (size_t)(n0 + r) * K + (k0 + sk), &Bb[c * 2048 + w * 512]);
      if (SPLIT) {
        gl_lds16(Ae + aPl + (size_t)(m0 + r) * lda + (k0 + sk), &Ab[8192 + c * 2048 + w * 512]);
        gl_lds16(We + bPl + (size_t)(n0 + r) * K + (k0 + sk), &Bb[8192 + c * 2048 + w * 512]);
      }
    }
    __syncthreads();
#pragma unroll
    for (int kc = 0; kc < 2; ++kc) {
      bf16x8 af[4], bq[4], afl[4], bql[4];
#pragma unroll
      for (int m = 0; m < 4; ++m) {
        int o = (wr * 64 + m * 16 + (l & 15)) * 64 + kc * 32 + ((l >> 4) << 3);
        af[m] = *(const bf16x8*)&Ab[o];
        if (SPLIT) afl[m] = *(const bf16x8*)&Ab[8192 + o];
      }
#pragma unroll
      for (int n = 0; n < 4; ++n) {
        int o = (wc * 64 + n * 16 + (l & 15)) * 64 + kc * 32 + ((l >> 4) << 3);
        bq[n] = *(const bf16x8*)&Bb[o];
        if (SPLIT) bql[n] = *(const bf16x8*)&Bb[8192 + o];
      }
#pragma unroll
      for (int m = 0; m < 4; ++m)
#pragma unroll
        for (int n = 0; n < 4; ++n)
          acc[m][n] = __builtin_amdgcn_mfma_f32_16x16x32_bf16(af[m], bq[n], acc[m][n], 0, 0, 0);
      if (SPLIT) {
#pragma unroll
        for (int m = 0; m < 4; ++m)
#pragma unroll
          for (int n = 0; n < 4; ++n)
            acc[m][n] = __builtin_amdgcn_mfma_f32_16x16x32_bf16(afl[m], bq[n], acc[m][n], 0, 0, 0);
#pragma unroll
        for (int m = 0; m < 4; ++m)
#pragma unroll
          for (int n = 0; n < 4; ++n)
            acc[m][n] = __builtin_amdgcn_mfma_f32_16x16x32_bf16(af[m], bql[n], acc[m][n], 0, 0, 0);
      }
    }
  }

  int cb = n0 + wc * 64 + (l & 15);
  int rb = m0 + wr * 64 + ((l >> 4) << 2);
#pragma unroll
  for (int m = 0; m < 4; ++m) {
#pragma unroll
    for (int n = 0; n < 4; ++n) {
      int gc = cb + n * 16;
      if (gc >= N) continue;
#pragma unroll
      for (int j = 0; j < 4; ++j) {
        int grl = rb + m * 16 + j;
        if (EXPERT && grl >= Mloc) continue;
        size_t gr = (size_t)(rowbase + grl);
        float v = acc[m][n][j];
        if (EPI == E_F32) ((float*)Cout)[gr * ldc + gc] = v;
        else if (EPI == E_ADDSRC) ((float*)Cout)[gr * ldc + gc] = v + SRC[gr * ldc + gc];
        else if (EPI == E_ADDINTO) ((float*)Cout)[gr * ldc + gc] += v;
        else if (EPI == E_SPLIT) {
          bf16 hi = cvt(v);
          ((bf16*)Cout)[gr * ldc + gc] = hi;
          ((bf16*)Cout)[cPl + gr * ldc + gc] = cvt(v - (float)hi);
        } else {  // E_ATOMIC: out[tok] += v * w_slot
          int tok = tok_of[gr];
          atomicAdd(&((float*)Cout)[(size_t)tok * ldc + gc], v * rowscale[gr]);
        }
      }
    }
  }
}

// ---------------- fused gate/up GEMM + silu*mul -> bf16 act. Tiles 128 rows x 64 im. (plain bf16)
template <bool GATHER>
__global__ __launch_bounds__(256, 2)
void ffn_act(const bf16* __restrict__ X,
             const bf16* __restrict__ WTg, const bf16* __restrict__ WTu, size_t wtsE,
             bf16* __restrict__ Out,
             const int* __restrict__ cnt, const int* __restrict__ offs,
             const int* __restrict__ tok_of, int M) {
  int e = GATHER ? blockIdx.z : 0;
  int Mloc = GATHER ? cnt[e] : M;
  int m0 = blockIdx.x * 128;
  if (m0 >= Mloc) return;
  int rowbase = GATHER ? offs[e] : 0;
  int n0 = blockIdx.y * 64;
  const bf16* Wg = WTg + (size_t)e * wtsE;
  const bf16* Wu = WTu + (size_t)e * wtsE;

  __shared__ __align__(16) bf16 Ab[128 * 64];
  __shared__ __align__(16) bf16 Bg[64 * 64];
  __shared__ __align__(16) bf16 Bu[64 * 64];

  int tid = threadIdx.x, w = tid >> 6, l = tid & 63;
  int fe = w * 512 + l * 8, sr = fe >> 6, sk = fe & 63;

  f32x4 ag[2][4], au[2][4];
#pragma unroll
  for (int i = 0; i < 2; ++i)
#pragma unroll
    for (int j = 0; j < 4; ++j) { ag[i][j] = (f32x4){0.f,0.f,0.f,0.f}; au[i][j] = (f32x4){0.f,0.f,0.f,0.f}; }

  for (int k0 = 0; k0 < 2048; k0 += 64) {
    __syncthreads();
#pragma unroll
    for (int c = 0; c < 4; ++c) {
      int r = c * 32 + sr;
      int tok;
      if (GATHER) {
        int slot = rowbase + m0 + r;
        slot = slot < NSLOT ? slot : NSLOT - 1;
        tok = tok_of[slot];
      } else tok = m0 + r;
      gl_lds16(X + (size_t)tok * 2048 + (k0 + sk), &Ab[c * 2048 + w * 512]);
    }
#pragma unroll
    for (int c = 0; c < 2; ++c) {
      int r = c * 32 + sr;
      gl_lds16(Wg + (size_t)(n0 + r) * 2048 + (k0 + sk), &Bg[c * 2048 + w * 512]);
      gl_lds16(Wu + (size_t)(n0 + r) * 2048 + (k0 + sk), &Bu[c * 2048 + w * 512]);
    }
    __syncthreads();
#pragma unroll
    for (int kc = 0; kc < 2; ++kc) {
      bf16x8 a[2], bg[4], bu[4];
#pragma unroll
      for (int m = 0; m < 2; ++m)
        a[m] = *(const bf16x8*)&Ab[(w * 32 + m * 16 + (l & 15)) * 64 + kc * 32 + ((l >> 4) << 3)];
#pragma unroll
      for (int n = 0; n < 4; ++n) {
        bg[n] = *(const bf16x8*)&Bg[(n * 16 + (l & 15)) * 64 + kc * 32 + ((l >> 4) << 3)];
        bu[n] = *(const bf16x8*)&Bu[(n * 16 + (l & 15)) * 64 + kc * 32 + ((l >> 4) << 3)];
      }
#pragma unroll
      for (int m = 0; m < 2; ++m)
#pragma unroll
        for (int n = 0; n < 4; ++n) {
          ag[m][n] = __builtin_amdgcn_mfma_f32_16x16x32_bf16(a[m], bg[n], ag[m][n], 0, 0, 0);
          au[m][n] = __builtin_amdgcn_mfma_f32_16x16x32_bf16(a[m], bu[n], au[m][n], 0, 0, 0);
        }
    }
  }
  int cb = n0 + (l & 15);
  int rb = m0 + w * 32 + ((l >> 4) << 2);
#pragma unroll
  for (int m = 0; m < 2; ++m)
#pragma unroll
    for (int n = 0; n < 4; ++n)
#pragma unroll
      for (int j = 0; j < 4; ++j) {
        int grl = rb + m * 16 + j;
        if (grl >= Mloc) continue;
        float g = ag[m][n][j], u = au[m][n][j];
        float s = g / (1.f + __expf(-g)) * u;
        Out[(size_t)(rowbase + grl) * 512 + (cb + n * 16)] = __float2bfloat16(s);
      }
}

// ---------------- RoPE + repack q/kv (split hi/lo in and out)
// Trig table computed in fp64 with fp32 rounding points matching numpy's host pipeline
// (inv_freq fp32, angle = fp32(pos*inv_freq), cos/sin correctly rounded) to minimize
// discrepancy vs the reference's np fp32 rope cache (routing-flip hazard).
__global__ __launch_bounds__(256) void rope_pack(const bf16* __restrict__ q, size_t qPl,
                                                 const bf16* __restrict__ kv, size_t kvPl,
                                                 const float* __restrict__ kva,
                                                 bf16* __restrict__ qf, bf16* __restrict__ kf, size_t fPl,
                                                 bf16* __restrict__ vvp, size_t vPl) {
  int t = blockIdx.x;
  int b = t >> 10, s = t & 1023;
  int tid = threadIdx.x;
  __shared__ float cs[64], sn[64], kr[64];
  if (tid < 64) {
    int i2 = tid & 31;
    float invf = (float)pow(10000.0, -(double)i2 / 32.0);  // == np fp32 inv_freq (correctly rounded)
    float fr = (float)s * invf;                            // np outer: single fp32 rounding
    cs[tid] = (float)cos((double)fr);                      // correctly-rounded cosf == np.cos
    sn[tid] = (float)sin((double)fr);
  }
  __syncthreads();
  if (tid < 64) {
    const float* kp = kva + (size_t)t * 576 + 512;
    float xv = kp[tid];
    float rh = (tid & 1) ? kp[tid - 1] : -kp[tid + 1];
    kr[tid] = xv * cs[tid] + rh * sn[tid];
  }
  __syncthreads();
  const bf16* qb = q + (size_t)t * 3072;
  const bf16* kvb = kv + (size_t)t * 4096;
  for (int idx = tid; idx < 16 * 192; idx += 256) {
    int hh = idx / 192, d = idx - hh * 192;
    size_t ob = ((size_t)(b * 16 + hh) * 1024 + s) * 192 + d;
    const bf16* qr = qb + hh * 192;
    float qv;
    if (d < 128) qv = (float)qr[d] + (float)qr[qPl + d];
    else {
      int dd = d - 128;
      float xv = (float)qr[128 + dd] + (float)qr[qPl + 128 + dd];
      float rh;
      if (dd & 1) rh = (float)qr[128 + dd - 1] + (float)qr[qPl + 128 + dd - 1];
      else rh = -((float)qr[128 + dd + 1] + (float)qr[qPl + 128 + dd + 1]);
      qv = xv * cs[dd] + rh * sn[dd];
    }
    bf16 qh = cvt(qv);
    qf[ob] = qh;
    qf[fPl + ob] = cvt(qv - (float)qh);
    float kvv;
    if (d < 128) kvv = (float)kvb[hh * 256 + d] + (float)kvb[kvPl + hh * 256 + d];
    else kvv = kr[d - 128];
    bf16 kh = cvt(kvv);
    kf[ob] = kh;
    kf[fPl + ob] = cvt(kvv - (float)kh);
  }
  for (int idx = tid; idx < 16 * 128; idx += 256) {
    int hh = idx >> 7, d = idx & 127;
    size_t ov = ((size_t)(b * 16 + hh) * 1024 + s) * 128 + d;
    float v = (float)kvb[hh * 256 + 128 + d] + (float)kvb[kvPl + hh * 256 + 128 + d];
    bf16 vh = cvt(v);
    vvp[ov] = vh;
    vvp[vPl + ov] = cvt(v - (float)vh);
  }
}

// ---------------- causal flash attention, split-bf16 precision, 64-row Q tiles, 4 waves x 16 rows
__global__ __launch_bounds__(256, 1)
void attn_k(const bf16* __restrict__ qf, const bf16* __restrict__ kf, size_t fPl,
            const bf16* __restrict__ vv, size_t vPl, bf16* __restrict__ ao, size_t aoPl) {
  int qt = blockIdx.x;
  int bh = blockIdx.y;
  int b = bh >> 4, h = bh & 15;
  int tid = threadIdx.x, w = tid >> 6, l = tid & 63;
  size_t base192 = (size_t)bh * 1024 * 192;
  size_t base128 = (size_t)bh * 1024 * 128;

  __shared__ __align__(16) bf16 Kt[2 * 64 * 200];
  __shared__ __align__(16) bf16 Vt[2 * 128 * 72];
  __shared__ __align__(16) bf16 Pt[2][4][16 * 72];

  bf16x8 aqh[6], aql[6];
  {
    const bf16* qp = qf + base192 + (size_t)(qt * 64 + w * 16 + (l & 15)) * 192 + ((l >> 4) << 3);
#pragma unroll
    for (int kc = 0; kc < 6; ++kc) {
      aqh[kc] = *(const bf16x8*)(qp + kc * 32);
      aql[kc] = *(const bf16x8*)(qp + fPl + kc * 32);
    }
  }
  f32x4 o[8];
#pragma unroll
  for (int i = 0; i < 8; ++i) o[i] = (f32x4){0.f, 0.f, 0.f, 0.f};
  float m_[4], s_[4];
#pragma unroll
  for (int j = 0; j < 4; ++j) { m_[j] = -3e38f; s_[j] = 0.f; }
  const float rs = 0.0721687836f;  // 1/sqrt(192)
  int qrow0 = qt * 64 + w * 16 + ((l >> 4) << 2);

  for (int kt = 0; kt <= qt; ++kt) {
    __syncthreads();
#pragma unroll
    for (int p = 0; p < 2; ++p) {
#pragma unroll
      for (int i = 0; i < 6; ++i) {
        int chunk = i * 256 + tid;
        int r = chunk / 24, cc = (chunk - r * 24) * 8;
        *(bf16x8*)&Kt[p * 12800 + r * 200 + cc] =
            *(const bf16x8*)(kf + p * fPl + base192 + (size_t)(kt * 64 + r) * 192 + cc);
      }
#pragma unroll
      for (int i = 0; i < 4; ++i) {
        int chunk = i * 256 + tid;
        int r = chunk >> 4, cc = (chunk & 15) * 8;
        bf16x8 vd = *(const bf16x8*)(vv + p * vPl + base128 + (size_t)(kt * 64 + r) * 128 + cc);
#pragma unroll
        for (int j = 0; j < 8; ++j) Vt[p * 9216 + (cc + j) * 72 + r] = *((const bf16*)&vd + j);
      }
    }
    __syncthreads();

    f32x4 sc[4];
#pragma unroll
    for (int nt = 0; nt < 4; ++nt) {
      sc[nt] = (f32x4){0.f, 0.f, 0.f, 0.f};
#pragma unroll
      for (int kc = 0; kc < 6; ++kc) {
        int ko = (nt * 16 + (l & 15)) * 200 + kc * 32 + ((l >> 4) << 3);
        bf16x8 bkh = *(const bf16x8*)&Kt[ko];
        bf16x8 bkl = *(const bf16x8*)&Kt[12800 + ko];
        sc[nt] = __builtin_amdgcn_mfma_f32_16x16x32_bf16(aqh[kc], bkh, sc[nt], 0, 0, 0);
        sc[nt] = __builtin_amdgcn_mfma_f32_16x16x32_bf16(aql[kc], bkh, sc[nt], 0, 0, 0);
        sc[nt] = __builtin_amdgcn_mfma_f32_16x16x32_bf16(aqh[kc], bkl, sc[nt], 0, 0, 0);
      }
    }
#pragma unroll
    for (int nt = 0; nt < 4; ++nt) {
      int kcol = kt * 64 + nt * 16 + (l & 15);
#pragma unroll
      for (int j = 0; j < 4; ++j) {
        float xv = sc[nt][j] * rs;
        if (kt == qt && kcol > qrow0 + j) xv = -1e30f;
        sc[nt][j] = xv;
      }
    }
#pragma unroll
    for (int j = 0; j < 4; ++j) {
      float mm = fmaxf(fmaxf(sc[0][j], sc[1][j]), fmaxf(sc[2][j], sc[3][j]));
#pragma unroll
      for (int d = 1; d < 16; d <<= 1) mm = fmaxf(mm, __shfl_xor(mm, d, 64));
      float mnew = fmaxf(m_[j], mm);
      float f = __expf(m_[j] - mnew);
      float ps = 0.f;
#pragma unroll
      for (int nt = 0; nt < 4; ++nt) {
        float p = __expf(sc[nt][j] - mnew);
        sc[nt][j] = p;
        ps += p;
      }
#pragma unroll
      for (int d = 1; d < 16; d <<= 1) ps += __shfl_xor(ps, d, 64);
      s_[j] = s_[j] * f + ps;
      m_[j] = mnew;
#pragma unroll
      for (int nt = 0; nt < 8; ++nt) o[nt][j] *= f;
    }
#pragma unroll
    for (int nt = 0; nt < 4; ++nt)
#pragma unroll
      for (int j = 0; j < 4; ++j) {
        float p = sc[nt][j];
        bf16 ph = cvt(p);
        int po = (((l >> 4) << 2) + j) * 72 + nt * 16 + (l & 15);
        Pt[0][w][po] = ph;
        Pt[1][w][po] = cvt(p - (float)ph);
      }
#pragma unroll
    for (int kc = 0; kc < 2; ++kc) {
      int pofs = (l & 15) * 72 + kc * 32 + ((l >> 4) << 3);
      bf16x8 aph = *(const bf16x8*)&Pt[0][w][pofs];
      bf16x8 apl = *(const bf16x8*)&Pt[1][w][pofs];
#pragma unroll
      for (int nt = 0; nt < 8; ++nt) {
        int vo = (nt * 16 + (l & 15)) * 72 + kc * 32 + ((l >> 4) << 3);
        bf16x8 bvh = *(const bf16x8*)&Vt[vo];
        bf16x8 bvl = *(const bf16x8*)&Vt[9216 + vo];
        o[nt] = __builtin_amdgcn_mfma_f32_16x16x32_bf16(aph, bvh, o[nt], 0, 0, 0);
        o[nt] = __builtin_amdgcn_mfma_f32_16x16x32_bf16(apl, bvh, o[nt], 0, 0, 0);
        o[nt] = __builtin_amdgcn_mfma_f32_16x16x32_bf16(aph, bvl, o[nt], 0, 0, 0);
      }
    }
  }
#pragma unroll
  for (int nt = 0; nt < 8; ++nt)
#pragma unroll
    for (int j = 0; j < 4; ++j) {
      size_t trow = (size_t)(b * 1024 + qrow0 + j);
      float v = o[nt][j] / s_[j];
      bf16 vh = cvt(v);
      size_t oi = trow * 2048 + h * 128 + nt * 16 + (l & 15);
      ao[oi] = vh;
      ao[aoPl + oi] = cvt(v - (float)vh);
    }
}

// ---------------- routing from fp32 h (re-does norm2 in fp32 so top-k decisions match reference)
__global__ __launch_bounds__(256) void route1(const float* __restrict__ h, const float* __restrict__ n2w,
                                              const float* __restrict__ gw, const float* __restrict__ gbias,
                                              float* __restrict__ wcomb, int* __restrict__ gmask,
                                              int* __restrict__ cnt) {
  int t = blockIdx.x;
  int tid = threadIdx.x, w = tid >> 6, l = tid & 63;
  const float* hp = h + (size_t)t * 2048;
  __shared__ float xr[2048];
  __shared__ float part[4];
  __shared__ float scs[16];
  float ss = 0.f;
  for (int i = tid; i < 512; i += 256) {
    float4 v = ((const float4*)hp)[i];
    ss += v.x * v.x + v.y * v.y + v.z * v.z + v.w * v.w;
  }
#pragma unroll
  for (int d = 1; d < 64; d <<= 1) ss += __shfl_xor(ss, d, 64);
  if (l == 0) part[w] = ss;
  __syncthreads();
  float rinv = rsqrtf((part[0] + part[1] + part[2] + part[3]) / 2048.f + 1e-6f);
  for (int i = tid; i < 512; i += 256) {
    float4 v = ((const float4*)hp)[i];
    float4 g = ((const float4*)n2w)[i];
    xr[i * 4 + 0] = v.x * rinv * g.x;
    xr[i * 4 + 1] = v.y * rinv * g.y;
    xr[i * 4 + 2] = v.z * rinv * g.z;
    xr[i * 4 + 3] = v.w * rinv * g.w;
  }
  __syncthreads();
#pragma unroll
  for (int ee = 0; ee < 4; ++ee) {
    int e = w * 4 + ee;
    float s = 0.f;
    for (int k = l; k < 2048; k += 64) s += xr[k] * gw[e * 2048 + k];
#pragma unroll
    for (int d = 1; d < 64; d <<= 1) s += __shfl_xor(s, d, 64);
    if (l == 0) scs[e] = 1.f / (1.f + expf(-s));
  }
  __syncthreads();
  if (tid == 0) {
    float scb[16];
#pragma unroll
    for (int e2 = 0; e2 < 16; ++e2) scb[e2] = scs[e2] + gbias[e2];
    float gsc[8];
#pragma unroll
    for (int g = 0; g < 8; ++g) gsc[g] = scb[2 * g] + scb[2 * g + 1];
    int mask = 0;
    for (int it = 0; it < 4; ++it) {
      float best = -3e38f;
      int bg = 0;
      for (int g = 0; g < 8; ++g)
        if (!((mask >> g) & 1) && gsc[g] > best) { best = gsc[g]; bg = g; }
      mask |= 1 << bg;
    }
    float wv[16];
#pragma unroll
    for (int e2 = 0; e2 < 16; ++e2) wv[e2] = 0.f;
    float wsum = 0.f;
    for (int g = 0; g < 8; ++g)
      if ((mask >> g) & 1) {
        wv[2 * g] = scs[2 * g];
        wv[2 * g + 1] = scs[2 * g + 1];
        wsum += scs[2 * g] + scs[2 * g + 1];
        atomicAdd(&cnt[2 * g], 1);
        atomicAdd(&cnt[2 * g + 1], 1);
      }
    float inv = 2.5f / (wsum + 1e-20f);
#pragma unroll
    for (int e2 = 0; e2 < 16; ++e2) wcomb[t * 16 + e2] = wv[e2] * inv;
    gmask[t] = mask;
  }
}

__global__ void route2(const int* __restrict__ cnt, int* __restrict__ offs) {
  if (threadIdx.x == 0) {
    int a = 0;
    for (int e = 0; e < 16; ++e) { offs[e] = a; a += cnt[e]; }
  }
}

__global__ void route3(const float* __restrict__ wcomb, const int* __restrict__ gmask,
                       const int* __restrict__ offs, int* __restrict__ fill,
                       int* __restrict__ tok_of, float* __restrict__ w_of) {
  int t = blockIdx.x * 256 + threadIdx.x;
  if (t >= TT) return;
  int mask = gmask[t];
  for (int g = 0; g < 8; ++g) {
    if (!((mask >> g) & 1)) continue;
    for (int p = 0; p < 2; ++p) {
      int e = 2 * g + p;
      int pos = atomicAdd(&fill[e], 1);
      int slot = offs[e] + pos;
      tok_of[slot] = t;
      w_of[slot] = wcomb[t * 16 + e];
    }
  }
}

extern "C" void kernel_launch(void* const* d_in, const int* in_sizes, int n_in,
                              void* d_out, int out_size, void* d_ws, size_t ws_size,
                              hipStream_t stream) {
  (void)in_sizes; (void)n_in; (void)out_size; (void)ws_size;
  const float* x        = (const float*)d_in[0];
  const float* norm1_w  = (const float*)d_in[1];
  const float* w_q_a    = (const float*)d_in[2];
  const float* q_a_norm = (const float*)d_in[3];
  const float* w_q_b    = (const float*)d_in[4];
  const float* w_kv_a   = (const float*)d_in[5];
  const float* kv_a_norm= (const float*)d_in[6];
  const float* w_kv_b   = (const float*)d_in[7];
  const float* w_out    = (const float*)d_in[8];
  const float* norm2_w  = (const float*)d_in[9];
  const float* gate_w   = (const float*)d_in[10];
  const float* gate_b   = (const float*)d_in[11];
  const float* w_gate   = (const float*)d_in[12];
  const float* w_up     = (const float*)d_in[13];
  const float* w_down   = (const float*)d_in[14];
  const float* ws_gate  = (const float*)d_in[15];
  const float* ws_up    = (const float*)d_in[16];
  const float* ws_down  = (const float*)d_in[17];
  float* out = (float*)d_out;   // doubles as the fp32 residual h
  char* ws = (char*)d_ws;

  size_t cur = 0;
  auto al = [&](size_t b) { size_t o = cur; cur = (cur + b + 255) & ~(size_t)255; return o; };

  // --- dedicated (never overlaid) routing metadata
  size_t o_wcomb= al((size_t)TT * 16 * 4);
  size_t o_gmask= al((size_t)TT * 4);
  size_t o_cnt  = al(256);
  size_t o_fill = al(256);
  size_t o_offs = al(256);
  size_t o_tok  = al((size_t)(NSLOT + 128) * 4);
  size_t o_wof  = al((size_t)(NSLOT + 128) * 4);

  // --- big union region R1
  size_t r1 = cur;
  // phase1 (attention path; dead after attention / w_out gemm)
  size_t o_qlat = al((size_t)TT * 512 * 4);        // fp32
  size_t o_kva  = al((size_t)TT * 576 * 4);        // fp32 (lives until rope_pack)
  size_t o_qn   = al((size_t)TT * 512 * 2 * 2);    // hi/lo
  size_t o_kvn  = al((size_t)TT * 512 * 2 * 2);
  size_t o_qbig = al((size_t)TT * 3072 * 2 * 2);
  size_t o_kvbig= al((size_t)TT * 4096 * 2 * 2);
  size_t o_qf   = al((size_t)TT * 3072 * 2 * 2);
  size_t o_kf   = al((size_t)TT * 3072 * 2 * 2);
  size_t o_vv   = al((size_t)TT * 2048 * 2 * 2);
  size_t r1end = cur;
  // phase2 (MoE; all launches after attention)
  cur = r1;
  size_t o_Wg  = al((size_t)16 * 512 * 2048 * 2);
  size_t o_Wu  = al((size_t)16 * 512 * 2048 * 2);
  size_t o_Wd  = al((size_t)16 * 2048 * 512 * 2);
  size_t o_act  = al((size_t)(NSLOT + 128) * 512 * 2);
  size_t o_acts = al((size_t)TT * 512 * 2);
  if (cur < r1end) cur = r1end;

  size_t o_h1 = al((size_t)TT * 2048 * 2 * 2);  // h1 hi/lo; reused as ao hi/lo after it dies
  size_t o_ao = o_h1;
  size_t o_xt = al((size_t)TT * 2048 * 2);
  size_t o_scr = al((size_t)2048 * 2048 * 2 * 2);  // transposed-weight scratch (max: w_out split)
  size_t o_scr2 = o_scr + (size_t)512 * 2048 * 2;  // second plain slot (ws_up)

  auto W = [&](size_t o) { return (bf16*)(ws + o); };
  auto F = [&](size_t o) { return (float*)(ws + o); };
  auto I = [&](size_t o) { return (int*)(ws + o); };

  // plane offsets (elements)
  const size_t PLh1 = (size_t)TT * 2048, PLqn = (size_t)TT * 512, PLqb = (size_t)TT * 3072,
               PLkvb = (size_t)TT * 4096, PLf = (size_t)TT * 3072, PLv = (size_t)TT * 2048,
               PLao = (size_t)TT * 2048;
  const size_t PLwqa = (size_t)512 * 2048, PLwkva = (size_t)640 * 2048, PLwqb = (size_t)3072 * 512,
               PLwkvb = (size_t)4096 * 512, PLwout = (size_t)2048 * 2048;

  hipMemsetAsync(ws + o_cnt, 0, 512, stream);  // cnt + fill

  rms_k<true><<<TT, 256, 0, stream>>>(x, 2048, 2048, norm1_w, W(o_h1), PLh1);

  // q_a / kv_a projections (split precision, fp32 out)
  transpose_cvt<true><<<dim3(16, 64, 1), 256, 0, stream>>>(w_q_a, W(o_scr), 2048, 512, 512);
  gemm128<E_F32, false, true><<<dim3(16, 4), 256, 0, stream>>>(W(o_h1), 2048, PLh1, W(o_scr), PLwqa, 0, 2048, F(o_qlat), 0, nullptr, TT, 512, 512, nullptr, nullptr, nullptr, nullptr);
  transpose_cvt<true><<<dim3(20, 64, 1), 256, 0, stream>>>(w_kv_a, W(o_scr), 2048, 576, 640);
  gemm128<E_F32, false, true><<<dim3(16, 5), 256, 0, stream>>>(W(o_h1), 2048, PLh1, W(o_scr), PLwkva, 0, 2048, F(o_kva), 0, nullptr, TT, 576, 576, nullptr, nullptr, nullptr, nullptr);

  rms_k<true><<<TT, 256, 0, stream>>>(F(o_qlat), 512, 512, q_a_norm, W(o_qn), PLqn);
  rms_k<true><<<TT, 256, 0, stream>>>(F(o_kva), 576, 512, kv_a_norm, W(o_kvn), PLqn);

  // q_b / kv_b projections (split in, split out)
  transpose_cvt<true><<<dim3(96, 16, 1), 256, 0, stream>>>(w_q_b, W(o_scr), 512, 3072, 3072);
  gemm128<E_SPLIT, false, true><<<dim3(16, 24), 256, 0, stream>>>(W(o_qn), 512, PLqn, W(o_scr), PLwqb, 0, 512, W(o_qbig), PLqb, nullptr, TT, 3072, 3072, nullptr, nullptr, nullptr, nullptr);
  transpose_cvt<true><<<dim3(128, 16, 1), 256, 0, stream>>>(w_kv_b, W(o_scr), 512, 4096, 4096);
  gemm128<E_SPLIT, false, true><<<dim3(16, 32), 256, 0, stream>>>(W(o_kvn), 512, PLqn, W(o_scr), PLwkvb, 0, 512, W(o_kvbig), PLkvb, nullptr, TT, 4096, 4096, nullptr, nullptr, nullptr, nullptr);

  rope_pack<<<TT, 256, 0, stream>>>(W(o_qbig), PLqb, W(o_kvbig), PLkvb, F(o_kva), W(o_qf), W(o_kf), PLf, W(o_vv), PLv);

  attn_k<<<dim3(16, 32), 256, 0, stream>>>(W(o_qf), W(o_kf), PLf, W(o_vv), PLv, W(o_ao), PLao);

  // out = ao @ w_out + x   (split precision; out doubles as residual h)
  transpose_cvt<true><<<dim3(64, 64, 1), 256, 0, stream>>>(w_out, W(o_scr), 2048, 2048, 2048);
  gemm128<E_ADDSRC, false, true><<<dim3(16, 16), 256, 0, stream>>>(W(o_ao), 2048, PLao, W(o_scr), PLwout, 0, 2048, out, 0, x, TT, 2048, 2048, nullptr, nullptr, nullptr, nullptr);

  rms_k<false><<<TT, 256, 0, stream>>>(out, 2048, 2048, norm2_w, W(o_xt), 0);

  route1<<<TT, 256, 0, stream>>>(out, norm2_w, gate_w, gate_b, F(o_wcomb), I(o_gmask), I(o_cnt));
  route2<<<1, 64, 0, stream>>>(I(o_cnt), I(o_offs));
  route3<<<TT / 256, 256, 0, stream>>>(F(o_wcomb), I(o_gmask), I(o_offs), I(o_fill), I(o_tok), F(o_wof));

  // shared FFN (plain bf16): acts = silu(xt@ws_gate)*(xt@ws_up); out += acts @ ws_down
  transpose_cvt<false><<<dim3(16, 64, 1), 256, 0, stream>>>(ws_gate, W(o_scr), 2048, 512, 512);
  transpose_cvt<false><<<dim3(16, 64, 1), 256, 0, stream>>>(ws_up, W(o_scr2), 2048, 512, 512);
  ffn_act<false><<<dim3(16, 8, 1), 256, 0, stream>>>(W(o_xt), W(o_scr), W(o_scr2), 0, W(o_acts), nullptr, nullptr, nullptr, TT);
  transpose_cvt<false><<<dim3(64, 16, 1), 256, 0, stream>>>(ws_down, W(o_scr), 512, 2048, 2048);
  gemm128<E_ADDINTO, false, false><<<dim3(16, 16), 256, 0, stream>>>(W(o_acts), 512, 0, W(o_scr), 0, 0, 512, out, 0, nullptr, TT, 2048, 2048, nullptr, nullptr, nullptr, nullptr);

  // expert FFN (grouped, plain bf16): act = silu(g)*u; out[tok] += (act @ w_down[e]) * w_slot
  transpose_cvt<false><<<dim3(16, 64, 16), 256, 0, stream>>>(w_gate, W(o_Wg), 2048, 512, 512);
  transpose_cvt<false><<<dim3(16, 64, 16), 256, 0, stream>>>(w_up, W(o_Wu), 2048, 512, 512);
  ffn_act<true><<<dim3(32, 8, 16), 256, 0, stream>>>(W(o_xt), W(o_Wg), W(o_Wu), (size_t)512 * 2048, W(o_act), I(o_cnt), I(o_offs), I(o_tok), 0);
  transpose_cvt<false><<<dim3(64, 16, 16), 256, 0, stream>>>(w_down, W(o_Wd), 512, 2048, 2048);
  gemm128<E_ATOMIC, true, false><<<dim3(32, 16, 16), 256, 0, stream>>>(W(o_act), 512, 0, W(o_Wd), 0, (size_t)2048 * 512, 512, out, 0, nullptr, 0, 2048, 2048, I(o_cnt), I(o_offs), F(o_wof), I(o_tok));
}

// Round 7
// 1795.895 us; speedup vs baseline: 1.0973x; 1.0973x over previous
//
#include <hip/hip_runtime.h>
#include <hip/hip_bf16.h>

typedef __attribute__((ext_vector_type(8))) __bf16 bf16x8;
typedef __attribute__((ext_vector_type(4))) float f32x4;
typedef __hip_bfloat16 bf16;

#define DEV __device__ __forceinline__

constexpr int TT = 2048;      // B*S tokens
constexpr int NSLOT = 16384;  // TT * TOPK(8)

DEV void gl_lds16(const void* g, void* l) {
  __builtin_amdgcn_global_load_lds((const __attribute__((address_space(1))) unsigned int*)g,
                                   (__attribute__((address_space(3))) unsigned int*)l, 16, 0, 0);
}

DEV bf16 cvt(float v) { return __float2bfloat16(v); }

// ---------------- transpose + convert: dst[c][r] = src[r][c] split hi/lo, rows padded to Cpad (zero fill)
template <bool SPLIT>
__global__ __launch_bounds__(256) void transpose_cvt(const float* __restrict__ src, bf16* __restrict__ dst,
                                                     int R, int C, int Cpad) {
  int e = blockIdx.z;  // SPLIT calls always use gridDim.z == 1
  src += (size_t)e * R * C;
  dst += (size_t)e * Cpad * R;
  size_t pl = (size_t)Cpad * R;  // lo plane offset (elements)
  __shared__ float t[32][33];
  int c0 = blockIdx.x * 32, r0 = blockIdx.y * 32;
  int tx = threadIdx.x & 31, ty = threadIdx.x >> 5;
#pragma unroll
  for (int i = 0; i < 4; ++i) {
    int r = ty + i * 8;
    int cc = c0 + tx;
    float v = (cc < C) ? src[(size_t)(r0 + r) * C + cc] : 0.f;
    t[r][tx] = v;
  }
  __syncthreads();
#pragma unroll
  for (int i = 0; i < 4; ++i) {
    int c = ty + i * 8;
    float v = t[tx][c];
    size_t idx = (size_t)(c0 + c) * R + (r0 + tx);
    bf16 hi = cvt(v);
    dst[idx] = hi;
    if (SPLIT) dst[pl + idx] = cvt(v - (float)hi);
  }
}

// ---------------- RMSNorm: dst = src*rsqrt(mean(src^2)+eps)*w, optional hi/lo split output
template <bool SPLIT>
__global__ __launch_bounds__(256) void rms_k(const float* __restrict__ src, int sst, int C,
                                             const float* __restrict__ wgt, bf16* __restrict__ dst,
                                             size_t dstPl) {
  int t = blockIdx.x;
  const float* sp = src + (size_t)t * sst;
  bf16* dp = dst + (size_t)t * C;
  int n4 = C >> 2;
  float ss = 0.f;
  for (int i = threadIdx.x; i < n4; i += 256) {
    float4 v = ((const float4*)sp)[i];
    ss += v.x * v.x + v.y * v.y + v.z * v.z + v.w * v.w;
  }
#pragma unroll
  for (int d = 1; d < 64; d <<= 1) ss += __shfl_xor(ss, d, 64);
  __shared__ float part[4];
  if ((threadIdx.x & 63) == 0) part[threadIdx.x >> 6] = ss;
  __syncthreads();
  float rinv = rsqrtf((part[0] + part[1] + part[2] + part[3]) / (float)C + 1e-6f);
  for (int i = threadIdx.x; i < n4; i += 256) {
    float4 v = ((const float4*)sp)[i];
    float4 g = ((const float4*)wgt)[i];
    float y[4] = {v.x * rinv * g.x, v.y * rinv * g.y, v.z * rinv * g.z, v.w * rinv * g.w};
    union { bf16 h[4]; short4 s; } uh, ul;
#pragma unroll
    for (int j = 0; j < 4; ++j) {
      bf16 hi = cvt(y[j]);
      uh.h[j] = hi;
      ul.h[j] = cvt(y[j] - (float)hi);
    }
    ((short4*)dp)[i] = uh.s;
    if (SPLIT) ((short4*)(dp + dstPl))[i] = ul.s;
  }
}

// ---------------- generic 128x128 bf16 GEMM, C = A[M,K] * WT[N,K]^T, optional split-bf16 precision
enum { E_F32 = 0, E_ADDSRC = 1, E_ADDINTO = 2, E_SPLIT = 3, E_BF16SC = 4 };

template <int EPI, bool EXPERT, bool SPLIT>
__global__ __launch_bounds__(256, 2)
void gemm128(const bf16* __restrict__ A, int lda, size_t aPl,
             const bf16* __restrict__ WT, size_t bPl, size_t wtsE, int K,
             void* __restrict__ Cout, size_t cPl, const float* __restrict__ SRC,
             int M, int N, int ldc,
             const int* __restrict__ cnt, const int* __restrict__ offs,
             const float* __restrict__ rowscale) {
  int e = EXPERT ? blockIdx.z : 0;
  int Mloc = EXPERT ? cnt[e] : M;
  int m0 = blockIdx.x * 128;
  if (EXPERT && m0 >= Mloc) return;
  int rowbase = EXPERT ? offs[e] : 0;
  const bf16* Ae = A + (size_t)rowbase * lda;
  const bf16* We = WT + (EXPERT ? (size_t)e * wtsE : 0);
  int n0 = blockIdx.y * 128;

  __shared__ __align__(16) bf16 Ab[(SPLIT ? 2 : 1) * 128 * 64];
  __shared__ __align__(16) bf16 Bb[(SPLIT ? 2 : 1) * 128 * 64];

  int tid = threadIdx.x, w = tid >> 6, l = tid & 63;
  int wr = w >> 1, wc = w & 1;
  int fe = w * 512 + l * 8, sr = fe >> 6, sk = fe & 63;

  f32x4 acc[4][4];
#pragma unroll
  for (int i = 0; i < 4; ++i)
#pragma unroll
    for (int j = 0; j < 4; ++j) acc[i][j] = (f32x4){0.f, 0.f, 0.f, 0.f};

  for (int k0 = 0; k0 < K; k0 += 64) {
    __syncthreads();
#pragma unroll
    for (int c = 0; c < 4; ++c) {
      int r = c * 32 + sr;
      gl_lds16(Ae + (size_t)(m0 + r) * lda + (k0 + sk), &Ab[c * 2048 + w * 512]);
      gl_lds16(We + (size_t)(n0 + r) * K + (k0 + sk), &Bb[c * 2048 + w * 512]);
      if (SPLIT) {
        gl_lds16(Ae + aPl + (size_t)(m0 + r) * lda + (k0 + sk), &Ab[8192 + c * 2048 + w * 512]);
        gl_lds16(We + bPl + (size_t)(n0 + r) * K + (k0 + sk), &Bb[8192 + c * 2048 + w * 512]);
      }
    }
    __syncthreads();
#pragma unroll
    for (int kc = 0; kc < 2; ++kc) {
      bf16x8 af[4], bq[4], afl[4], bql[4];
#pragma unroll
      for (int m = 0; m < 4; ++m) {
        int o = (wr * 64 + m * 16 + (l & 15)) * 64 + kc * 32 + ((l >> 4) << 3);
        af[m] = *(const bf16x8*)&Ab[o];
        if (SPLIT) afl[m] = *(const bf16x8*)&Ab[8192 + o];
      }
#pragma unroll
      for (int n = 0; n < 4; ++n) {
        int o = (wc * 64 + n * 16 + (l & 15)) * 64 + kc * 32 + ((l >> 4) << 3);
        bq[n] = *(const bf16x8*)&Bb[o];
        if (SPLIT) bql[n] = *(const bf16x8*)&Bb[8192 + o];
      }
#pragma unroll
      for (int m = 0; m < 4; ++m)
#pragma unroll
        for (int n = 0; n < 4; ++n)
          acc[m][n] = __builtin_amdgcn_mfma_f32_16x16x32_bf16(af[m], bq[n], acc[m][n], 0, 0, 0);
      if (SPLIT) {
#pragma unroll
        for (int m = 0; m < 4; ++m)
#pragma unroll
          for (int n = 0; n < 4; ++n)
            acc[m][n] = __builtin_amdgcn_mfma_f32_16x16x32_bf16(afl[m], bq[n], acc[m][n], 0, 0, 0);
#pragma unroll
        for (int m = 0; m < 4; ++m)
#pragma unroll
          for (int n = 0; n < 4; ++n)
            acc[m][n] = __builtin_amdgcn_mfma_f32_16x16x32_bf16(af[m], bql[n], acc[m][n], 0, 0, 0);
      }
    }
  }

  int cb = n0 + wc * 64 + (l & 15);
  int rb = m0 + wr * 64 + ((l >> 4) << 2);
#pragma unroll
  for (int m = 0; m < 4; ++m) {
#pragma unroll
    for (int n = 0; n < 4; ++n) {
      int gc = cb + n * 16;
      if (gc >= N) continue;
#pragma unroll
      for (int j = 0; j < 4; ++j) {
        int grl = rb + m * 16 + j;
        if (EXPERT && grl >= Mloc) continue;
        size_t gr = (size_t)(rowbase + grl);
        float v = acc[m][n][j];
        if (EPI == E_F32) ((float*)Cout)[gr * ldc + gc] = v;
        else if (EPI == E_ADDSRC) ((float*)Cout)[gr * ldc + gc] = v + SRC[gr * ldc + gc];
        else if (EPI == E_ADDINTO) ((float*)Cout)[gr * ldc + gc] += v;
        else if (EPI == E_SPLIT) {
          bf16 hi = cvt(v);
          ((bf16*)Cout)[gr * ldc + gc] = hi;
          ((bf16*)Cout)[cPl + gr * ldc + gc] = cvt(v - (float)hi);
        } else {  // E_BF16SC: eo[slot] = bf16(v * w_slot)
          ((bf16*)Cout)[gr * ldc + gc] = cvt(v * rowscale[gr]);
        }
      }
    }
  }
}

// ---------------- fused gate/up GEMM + silu*mul -> bf16 act. Tiles 128 rows x 64 im. (plain bf16)
template <bool GATHER>
__global__ __launch_bounds__(256, 2)
void ffn_act(const bf16* __restrict__ X,
             const bf16* __restrict__ WTg, const bf16* __restrict__ WTu, size_t wtsE,
             bf16* __restrict__ Out,
             const int* __restrict__ cnt, const int* __restrict__ offs,
             const int* __restrict__ tok_of, int M) {
  int e = GATHER ? blockIdx.z : 0;
  int Mloc = GATHER ? cnt[e] : M;
  int m0 = blockIdx.x * 128;
  if (m0 >= Mloc) return;
  int rowbase = GATHER ? offs[e] : 0;
  int n0 = blockIdx.y * 64;
  const bf16* Wg = WTg + (size_t)e * wtsE;
  const bf16* Wu = WTu + (size_t)e * wtsE;

  __shared__ __align__(16) bf16 Ab[128 * 64];
  __shared__ __align__(16) bf16 Bg[64 * 64];
  __shared__ __align__(16) bf16 Bu[64 * 64];

  int tid = threadIdx.x, w = tid >> 6, l = tid & 63;
  int fe = w * 512 + l * 8, sr = fe >> 6, sk = fe & 63;

  f32x4 ag[2][4], au[2][4];
#pragma unroll
  for (int i = 0; i < 2; ++i)
#pragma unroll
    for (int j = 0; j < 4; ++j) { ag[i][j] = (f32x4){0.f,0.f,0.f,0.f}; au[i][j] = (f32x4){0.f,0.f,0.f,0.f}; }

  for (int k0 = 0; k0 < 2048; k0 += 64) {
    __syncthreads();
#pragma unroll
    for (int c = 0; c < 4; ++c) {
      int r = c * 32 + sr;
      int tok;
      if (GATHER) {
        int slot = rowbase + m0 + r;
        slot = slot < NSLOT ? slot : NSLOT - 1;
        tok = tok_of[slot];
      } else tok = m0 + r;
      gl_lds16(X + (size_t)tok * 2048 + (k0 + sk), &Ab[c * 2048 + w * 512]);
    }
#pragma unroll
    for (int c = 0; c < 2; ++c) {
      int r = c * 32 + sr;
      gl_lds16(Wg + (size_t)(n0 + r) * 2048 + (k0 + sk), &Bg[c * 2048 + w * 512]);
      gl_lds16(Wu + (size_t)(n0 + r) * 2048 + (k0 + sk), &Bu[c * 2048 + w * 512]);
    }
    __syncthreads();
#pragma unroll
    for (int kc = 0; kc < 2; ++kc) {
      bf16x8 a[2], bg[4], bu[4];
#pragma unroll
      for (int m = 0; m < 2; ++m)
        a[m] = *(const bf16x8*)&Ab[(w * 32 + m * 16 + (l & 15)) * 64 + kc * 32 + ((l >> 4) << 3)];
#pragma unroll
      for (int n = 0; n < 4; ++n) {
        bg[n] = *(const bf16x8*)&Bg[(n * 16 + (l & 15)) * 64 + kc * 32 + ((l >> 4) << 3)];
        bu[n] = *(const bf16x8*)&Bu[(n * 16 + (l & 15)) * 64 + kc * 32 + ((l >> 4) << 3)];
      }
#pragma unroll
      for (int m = 0; m < 2; ++m)
#pragma unroll
        for (int n = 0; n < 4; ++n) {
          ag[m][n] = __builtin_amdgcn_mfma_f32_16x16x32_bf16(a[m], bg[n], ag[m][n], 0, 0, 0);
          au[m][n] = __builtin_amdgcn_mfma_f32_16x16x32_bf16(a[m], bu[n], au[m][n], 0, 0, 0);
        }
    }
  }
  int cb = n0 + (l & 15);
  int rb = m0 + w * 32 + ((l >> 4) << 2);
#pragma unroll
  for (int m = 0; m < 2; ++m)
#pragma unroll
    for (int n = 0; n < 4; ++n)
#pragma unroll
      for (int j = 0; j < 4; ++j) {
        int grl = rb + m * 16 + j;
        if (grl >= Mloc) continue;
        float g = ag[m][n][j], u = au[m][n][j];
        float s = g / (1.f + __expf(-g)) * u;
        Out[(size_t)(rowbase + grl) * 512 + (cb + n * 16)] = __float2bfloat16(s);
      }
}

// ---------------- RoPE + repack q/kv (split hi/lo in and out)
__global__ __launch_bounds__(256) void rope_pack(const bf16* __restrict__ q, size_t qPl,
                                                 const bf16* __restrict__ kv, size_t kvPl,
                                                 const float* __restrict__ kva,
                                                 bf16* __restrict__ qf, bf16* __restrict__ kf, size_t fPl,
                                                 bf16* __restrict__ vvp, size_t vPl) {
  int t = blockIdx.x;
  int b = t >> 10, s = t & 1023;
  int tid = threadIdx.x;
  __shared__ float cs[64], sn[64], kr[64];
  if (tid < 64) {
    int i2 = tid & 31;
    float invf = (float)pow(10000.0, -(double)i2 / 32.0);  // == np fp32 inv_freq (correctly rounded)
    float fr = (float)s * invf;                            // np outer: single fp32 rounding
    cs[tid] = (float)cos((double)fr);                      // correctly-rounded cosf == np.cos
    sn[tid] = (float)sin((double)fr);
  }
  __syncthreads();
  if (tid < 64) {
    const float* kp = kva + (size_t)t * 576 + 512;
    float xv = kp[tid];
    float rh = (tid & 1) ? kp[tid - 1] : -kp[tid + 1];
    kr[tid] = xv * cs[tid] + rh * sn[tid];
  }
  __syncthreads();
  const bf16* qb = q + (size_t)t * 3072;
  const bf16* kvb = kv + (size_t)t * 4096;
  for (int idx = tid; idx < 16 * 192; idx += 256) {
    int hh = idx / 192, d = idx - hh * 192;
    size_t ob = ((size_t)(b * 16 + hh) * 1024 + s) * 192 + d;
    const bf16* qr = qb + hh * 192;
    float qv;
    if (d < 128) qv = (float)qr[d] + (float)qr[qPl + d];
    else {
      int dd = d - 128;
      float xv = (float)qr[128 + dd] + (float)qr[qPl + 128 + dd];
      float rh;
      if (dd & 1) rh = (float)qr[128 + dd - 1] + (float)qr[qPl + 128 + dd - 1];
      else rh = -((float)qr[128 + dd + 1] + (float)qr[qPl + 128 + dd + 1]);
      qv = xv * cs[dd] + rh * sn[dd];
    }
    bf16 qh = cvt(qv);
    qf[ob] = qh;
    qf[fPl + ob] = cvt(qv - (float)qh);
    float kvv;
    if (d < 128) kvv = (float)kvb[hh * 256 + d] + (float)kvb[kvPl + hh * 256 + d];
    else kvv = kr[d - 128];
    bf16 kh = cvt(kvv);
    kf[ob] = kh;
    kf[fPl + ob] = cvt(kvv - (float)kh);
  }
  for (int idx = tid; idx < 16 * 128; idx += 256) {
    int hh = idx >> 7, d = idx & 127;
    size_t ov = ((size_t)(b * 16 + hh) * 1024 + s) * 128 + d;
    float v = (float)kvb[hh * 256 + 128 + d] + (float)kvb[kvPl + hh * 256 + 128 + d];
    bf16 vh = cvt(v);
    vvp[ov] = vh;
    vvp[vPl + ov] = cvt(v - (float)vh);
  }
}

// ---------------- causal flash attention, split-bf16 precision, 64-row Q tiles, 4 waves x 16 rows
__global__ __launch_bounds__(256, 1)
void attn_k(const bf16* __restrict__ qf, const bf16* __restrict__ kf, size_t fPl,
            const bf16* __restrict__ vv, size_t vPl, bf16* __restrict__ ao, size_t aoPl) {
  int qt = blockIdx.x;
  int bh = blockIdx.y;
  int b = bh >> 4, h = bh & 15;
  int tid = threadIdx.x, w = tid >> 6, l = tid & 63;
  size_t base192 = (size_t)bh * 1024 * 192;
  size_t base128 = (size_t)bh * 1024 * 128;

  __shared__ __align__(16) bf16 Kt[2 * 64 * 200];
  __shared__ __align__(16) bf16 Vt[2 * 128 * 72];
  __shared__ __align__(16) bf16 Pt[2][4][16 * 72];

  bf16x8 aqh[6], aql[6];
  {
    const bf16* qp = qf + base192 + (size_t)(qt * 64 + w * 16 + (l & 15)) * 192 + ((l >> 4) << 3);
#pragma unroll
    for (int kc = 0; kc < 6; ++kc) {
      aqh[kc] = *(const bf16x8*)(qp + kc * 32);
      aql[kc] = *(const bf16x8*)(qp + fPl + kc * 32);
    }
  }
  f32x4 o[8];
#pragma unroll
  for (int i = 0; i < 8; ++i) o[i] = (f32x4){0.f, 0.f, 0.f, 0.f};
  float m_[4], s_[4];
#pragma unroll
  for (int j = 0; j < 4; ++j) { m_[j] = -3e38f; s_[j] = 0.f; }
  const float rs = 0.0721687836f;  // 1/sqrt(192)
  int qrow0 = qt * 64 + w * 16 + ((l >> 4) << 2);

  for (int kt = 0; kt <= qt; ++kt) {
    __syncthreads();
#pragma unroll
    for (int p = 0; p < 2; ++p) {
#pragma unroll
      for (int i = 0; i < 6; ++i) {
        int chunk = i * 256 + tid;
        int r = chunk / 24, cc = (chunk - r * 24) * 8;
        *(bf16x8*)&Kt[p * 12800 + r * 200 + cc] =
            *(const bf16x8*)(kf + p * fPl + base192 + (size_t)(kt * 64 + r) * 192 + cc);
      }
#pragma unroll
      for (int i = 0; i < 4; ++i) {
        int chunk = i * 256 + tid;
        int r = chunk >> 4, cc = (chunk & 15) * 8;
        bf16x8 vd = *(const bf16x8*)(vv + p * vPl + base128 + (size_t)(kt * 64 + r) * 128 + cc);
#pragma unroll
        for (int j = 0; j < 8; ++j) Vt[p * 9216 + (cc + j) * 72 + r] = *((const bf16*)&vd + j);
      }
    }
    __syncthreads();

    f32x4 sc[4];
#pragma unroll
    for (int nt = 0; nt < 4; ++nt) {
      sc[nt] = (f32x4){0.f, 0.f, 0.f, 0.f};
#pragma unroll
      for (int kc = 0; kc < 6; ++kc) {
        int ko = (nt * 16 + (l & 15)) * 200 + kc * 32 + ((l >> 4) << 3);
        bf16x8 bkh = *(const bf16x8*)&Kt[ko];
        bf16x8 bkl = *(const bf16x8*)&Kt[12800 + ko];
        sc[nt] = __builtin_amdgcn_mfma_f32_16x16x32_bf16(aqh[kc], bkh, sc[nt], 0, 0, 0);
        sc[nt] = __builtin_amdgcn_mfma_f32_16x16x32_bf16(aql[kc], bkh, sc[nt], 0, 0, 0);
        sc[nt] = __builtin_amdgcn_mfma_f32_16x16x32_bf16(aqh[kc], bkl, sc[nt], 0, 0, 0);
      }
    }
#pragma unroll
    for (int nt = 0; nt < 4; ++nt) {
      int kcol = kt * 64 + nt * 16 + (l & 15);
#pragma unroll
      for (int j = 0; j < 4; ++j) {
        float xv = sc[nt][j] * rs;
        if (kt == qt && kcol > qrow0 + j) xv = -1e30f;
        sc[nt][j] = xv;
      }
    }
#pragma unroll
    for (int j = 0; j < 4; ++j) {
      float mm = fmaxf(fmaxf(sc[0][j], sc[1][j]), fmaxf(sc[2][j], sc[3][j]));
#pragma unroll
      for (int d = 1; d < 16; d <<= 1) mm = fmaxf(mm, __shfl_xor(mm, d, 64));
      float mnew = fmaxf(m_[j], mm);
      float f = __expf(m_[j] - mnew);
      float ps = 0.f;
#pragma unroll
      for (int nt = 0; nt < 4; ++nt) {
        float p = __expf(sc[nt][j] - mnew);
        sc[nt][j] = p;
        ps += p;
      }
#pragma unroll
      for (int d = 1; d < 16; d <<= 1) ps += __shfl_xor(ps, d, 64);
      s_[j] = s_[j] * f + ps;
      m_[j] = mnew;
#pragma unroll
      for (int nt = 0; nt < 8; ++nt) o[nt][j] *= f;
    }
#pragma unroll
    for (int nt = 0; nt < 4; ++nt)
#pragma unroll
      for (int j = 0; j < 4; ++j) {
        float p = sc[nt][j];
        bf16 ph = cvt(p);
        int po = (((l >> 4) << 2) + j) * 72 + nt * 16 + (l & 15);
        Pt[0][w][po] = ph;
        Pt[1][w][po] = cvt(p - (float)ph);
      }
#pragma unroll
    for (int kc = 0; kc < 2; ++kc) {
      int pofs = (l & 15) * 72 + kc * 32 + ((l >> 4) << 3);
      bf16x8 aph = *(const bf16x8*)&Pt[0][w][pofs];
      bf16x8 apl = *(const bf16x8*)&Pt[1][w][pofs];
#pragma unroll
      for (int nt = 0; nt < 8; ++nt) {
        int vo = (nt * 16 + (l & 15)) * 72 + kc * 32 + ((l >> 4) << 3);
        bf16x8 bvh = *(const bf16x8*)&Vt[vo];
        bf16x8 bvl = *(const bf16x8*)&Vt[9216 + vo];
        o[nt] = __builtin_amdgcn_mfma_f32_16x16x32_bf16(aph, bvh, o[nt], 0, 0, 0);
        o[nt] = __builtin_amdgcn_mfma_f32_16x16x32_bf16(apl, bvh, o[nt], 0, 0, 0);
        o[nt] = __builtin_amdgcn_mfma_f32_16x16x32_bf16(aph, bvl, o[nt], 0, 0, 0);
      }
    }
  }
#pragma unroll
  for (int nt = 0; nt < 8; ++nt)
#pragma unroll
    for (int j = 0; j < 4; ++j) {
      size_t trow = (size_t)(b * 1024 + qrow0 + j);
      float v = o[nt][j] / s_[j];
      bf16 vh = cvt(v);
      size_t oi = trow * 2048 + h * 128 + nt * 16 + (l & 15);
      ao[oi] = vh;
      ao[aoPl + oi] = cvt(v - (float)vh);
    }
}

// ---------------- routing from fp32 h (re-does norm2 in fp32 so top-k decisions match reference)
__global__ __launch_bounds__(256) void route1(const float* __restrict__ h, const float* __restrict__ n2w,
                                              const float* __restrict__ gw, const float* __restrict__ gbias,
                                              float* __restrict__ wcomb, int* __restrict__ gmask,
                                              int* __restrict__ cnt) {
  int t = blockIdx.x;
  int tid = threadIdx.x, w = tid >> 6, l = tid & 63;
  const float* hp = h + (size_t)t * 2048;
  __shared__ float xr[2048];
  __shared__ float part[4];
  __shared__ float scs[16];
  float ss = 0.f;
  for (int i = tid; i < 512; i += 256) {
    float4 v = ((const float4*)hp)[i];
    ss += v.x * v.x + v.y * v.y + v.z * v.z + v.w * v.w;
  }
#pragma unroll
  for (int d = 1; d < 64; d <<= 1) ss += __shfl_xor(ss, d, 64);
  if (l == 0) part[w] = ss;
  __syncthreads();
  float rinv = rsqrtf((part[0] + part[1] + part[2] + part[3]) / 2048.f + 1e-6f);
  for (int i = tid; i < 512; i += 256) {
    float4 v = ((const float4*)hp)[i];
    float4 g = ((const float4*)n2w)[i];
    xr[i * 4 + 0] = v.x * rinv * g.x;
    xr[i * 4 + 1] = v.y * rinv * g.y;
    xr[i * 4 + 2] = v.z * rinv * g.z;
    xr[i * 4 + 3] = v.w * rinv * g.w;
  }
  __syncthreads();
#pragma unroll
  for (int ee = 0; ee < 4; ++ee) {
    int e = w * 4 + ee;
    float s = 0.f;
    for (int k = l; k < 2048; k += 64) s += xr[k] * gw[e * 2048 + k];
#pragma unroll
    for (int d = 1; d < 64; d <<= 1) s += __shfl_xor(s, d, 64);
    if (l == 0) scs[e] = 1.f / (1.f + expf(-s));
  }
  __syncthreads();
  if (tid == 0) {
    float scb[16];
#pragma unroll
    for (int e2 = 0; e2 < 16; ++e2) scb[e2] = scs[e2] + gbias[e2];
    float gsc[8];
#pragma unroll
    for (int g = 0; g < 8; ++g) gsc[g] = scb[2 * g] + scb[2 * g + 1];
    int mask = 0;
    for (int it = 0; it < 4; ++it) {
      float best = -3e38f;
      int bg = 0;
      for (int g = 0; g < 8; ++g)
        if (!((mask >> g) & 1) && gsc[g] > best) { best = gsc[g]; bg = g; }
      mask |= 1 << bg;
    }
    float wv[16];
#pragma unroll
    for (int e2 = 0; e2 < 16; ++e2) wv[e2] = 0.f;
    float wsum = 0.f;
    for (int g = 0; g < 8; ++g)
      if ((mask >> g) & 1) {
        wv[2 * g] = scs[2 * g];
        wv[2 * g + 1] = scs[2 * g + 1];
        wsum += scs[2 * g] + scs[2 * g + 1];
        atomicAdd(&cnt[2 * g], 1);
        atomicAdd(&cnt[2 * g + 1], 1);
      }
    float inv = 2.5f / (wsum + 1e-20f);
#pragma unroll
    for (int e2 = 0; e2 < 16; ++e2) wcomb[t * 16 + e2] = wv[e2] * inv;
    gmask[t] = mask;
  }
}

__global__ void route2(const int* __restrict__ cnt, int* __restrict__ offs) {
  if (threadIdx.x == 0) {
    int a = 0;
    for (int e = 0; e < 16; ++e) { offs[e] = a; a += cnt[e]; }
  }
}

__global__ void route3(const float* __restrict__ wcomb, const int* __restrict__ gmask,
                       const int* __restrict__ offs, int* __restrict__ fill,
                       int* __restrict__ tok_of, float* __restrict__ w_of, int* __restrict__ slot_of) {
  int t = blockIdx.x * 256 + threadIdx.x;
  if (t >= TT) return;
  int mask = gmask[t];
  int j = 0;
  for (int g = 0; g < 8; ++g) {
    if (!((mask >> g) & 1)) continue;
    for (int p = 0; p < 2; ++p) {
      int e = 2 * g + p;
      int pos = atomicAdd(&fill[e], 1);
      int slot = offs[e] + pos;
      tok_of[slot] = t;
      w_of[slot] = wcomb[t * 16 + e];
      slot_of[t * 8 + j] = slot;
      ++j;
    }
  }
}

// ---------------- final: out[t] += sum of 8 pre-weighted expert rows (out already = h + shared)
__global__ __launch_bounds__(256) void finalk(const bf16* __restrict__ eo,
                                              const int* __restrict__ slot_of, float* __restrict__ out) {
  int t = blockIdx.x, tid = threadIdx.x;
  float* op = out + (size_t)t * 2048;
  float a[8];
  float4 h0 = ((const float4*)op)[tid * 2];
  float4 h1v = ((const float4*)op)[tid * 2 + 1];
  a[0] = h0.x; a[1] = h0.y; a[2] = h0.z; a[3] = h0.w;
  a[4] = h1v.x; a[5] = h1v.y; a[6] = h1v.z; a[7] = h1v.w;
#pragma unroll
  for (int j = 0; j < 8; ++j) {
    int slot = slot_of[t * 8 + j];
    bf16x8 v = ((const bf16x8*)(eo + (size_t)slot * 2048))[tid];
#pragma unroll
    for (int i = 0; i < 8; ++i) a[i] += (float)v[i];
  }
  ((float4*)op)[tid * 2] = make_float4(a[0], a[1], a[2], a[3]);
  ((float4*)op)[tid * 2 + 1] = make_float4(a[4], a[5], a[6], a[7]);
}

extern "C" void kernel_launch(void* const* d_in, const int* in_sizes, int n_in,
                              void* d_out, int out_size, void* d_ws, size_t ws_size,
                              hipStream_t stream) {
  (void)in_sizes; (void)n_in; (void)out_size; (void)ws_size;
  const float* x        = (const float*)d_in[0];
  const float* norm1_w  = (const float*)d_in[1];
  const float* w_q_a    = (const float*)d_in[2];
  const float* q_a_norm = (const float*)d_in[3];
  const float* w_q_b    = (const float*)d_in[4];
  const float* w_kv_a   = (const float*)d_in[5];
  const float* kv_a_norm= (const float*)d_in[6];
  const float* w_kv_b   = (const float*)d_in[7];
  const float* w_out    = (const float*)d_in[8];
  const float* norm2_w  = (const float*)d_in[9];
  const float* gate_w   = (const float*)d_in[10];
  const float* gate_b   = (const float*)d_in[11];
  const float* w_gate   = (const float*)d_in[12];
  const float* w_up     = (const float*)d_in[13];
  const float* w_down   = (const float*)d_in[14];
  const float* ws_gate  = (const float*)d_in[15];
  const float* ws_up    = (const float*)d_in[16];
  const float* ws_down  = (const float*)d_in[17];
  float* out = (float*)d_out;   // doubles as the fp32 residual h
  char* ws = (char*)d_ws;

  size_t cur = 0;
  auto al = [&](size_t b) { size_t o = cur; cur = (cur + b + 255) & ~(size_t)255; return o; };

  // --- dedicated (never overlaid) routing metadata
  size_t o_wcomb= al((size_t)TT * 16 * 4);
  size_t o_gmask= al((size_t)TT * 4);
  size_t o_cnt  = al(256);
  size_t o_fill = al(256);
  size_t o_offs = al(256);
  size_t o_tok  = al((size_t)(NSLOT + 128) * 4);
  size_t o_wof  = al((size_t)(NSLOT + 128) * 4);
  size_t o_slot = al((size_t)TT * 8 * 4);

  // --- big union region R1
  size_t r1 = cur;
  // phase1 (attention path; dead after attention / w_out gemm)
  size_t o_qlat = al((size_t)TT * 512 * 4);        // fp32
  size_t o_kva  = al((size_t)TT * 576 * 4);        // fp32 (lives until rope_pack)
  size_t o_qn   = al((size_t)TT * 512 * 2 * 2);    // hi/lo
  size_t o_kvn  = al((size_t)TT * 512 * 2 * 2);
  size_t o_qbig = al((size_t)TT * 3072 * 2 * 2);
  size_t o_kvbig= al((size_t)TT * 4096 * 2 * 2);
  size_t o_qf   = al((size_t)TT * 3072 * 2 * 2);
  size_t o_kf   = al((size_t)TT * 3072 * 2 * 2);
  size_t o_vv   = al((size_t)TT * 2048 * 2 * 2);
  size_t r1end = cur;
  // phase2 (MoE; all launches after attention). Reuse trick:
  //  - ffn_act reads Wg,Wu -> then w_down is transposed into the (dead) Wg slot
  //  - eo exactly occupies the (dead) Wu+Wd slots (33.55MB + 33.55MB = 67.1MB = NSLOT*2048*2)
  cur = r1;
  size_t o_Wg  = al((size_t)16 * 512 * 2048 * 2);   // later: Wd2 (transposed w_down)
  size_t o_Wu  = al((size_t)16 * 512 * 2048 * 2);   // later: eo (spans Wu+Wd slots)
  size_t o_Wd  = al((size_t)16 * 2048 * 512 * 2);
  size_t o_act  = al((size_t)(NSLOT + 128) * 512 * 2);
  size_t o_acts = al((size_t)TT * 512 * 2);
  if (cur < r1end) cur = r1end;
  size_t o_Wd2 = o_Wg;  // w_down transposed (after ffn_act done with Wg)
  size_t o_eo  = o_Wu;  // expert outputs (after ffn_act done with Wu; spans Wu+Wd)

  size_t o_h1 = al((size_t)TT * 2048 * 2 * 2);  // h1 hi/lo; reused as ao hi/lo after it dies
  size_t o_ao = o_h1;
  size_t o_xt = al((size_t)TT * 2048 * 2);
  size_t o_scr = al((size_t)2048 * 2048 * 2 * 2);  // transposed-weight scratch (max: w_out split)
  size_t o_scr2 = o_scr + (size_t)512 * 2048 * 2;  // second plain slot (ws_up)

  auto W = [&](size_t o) { return (bf16*)(ws + o); };
  auto F = [&](size_t o) { return (float*)(ws + o); };
  auto I = [&](size_t o) { return (int*)(ws + o); };

  // plane offsets (elements)
  const size_t PLh1 = (size_t)TT * 2048, PLqn = (size_t)TT * 512, PLqb = (size_t)TT * 3072,
               PLkvb = (size_t)TT * 4096, PLf = (size_t)TT * 3072, PLv = (size_t)TT * 2048,
               PLao = (size_t)TT * 2048;
  const size_t PLwqa = (size_t)512 * 2048, PLwkva = (size_t)640 * 2048, PLwqb = (size_t)3072 * 512,
               PLwkvb = (size_t)4096 * 512, PLwout = (size_t)2048 * 2048;

  hipMemsetAsync(ws + o_cnt, 0, 512, stream);  // cnt + fill

  rms_k<true><<<TT, 256, 0, stream>>>(x, 2048, 2048, norm1_w, W(o_h1), PLh1);

  // q_a / kv_a projections (split precision, fp32 out)
  transpose_cvt<true><<<dim3(16, 64, 1), 256, 0, stream>>>(w_q_a, W(o_scr), 2048, 512, 512);
  gemm128<E_F32, false, true><<<dim3(16, 4), 256, 0, stream>>>(W(o_h1), 2048, PLh1, W(o_scr), PLwqa, 0, 2048, F(o_qlat), 0, nullptr, TT, 512, 512, nullptr, nullptr, nullptr);
  transpose_cvt<true><<<dim3(20, 64, 1), 256, 0, stream>>>(w_kv_a, W(o_scr), 2048, 576, 640);
  gemm128<E_F32, false, true><<<dim3(16, 5), 256, 0, stream>>>(W(o_h1), 2048, PLh1, W(o_scr), PLwkva, 0, 2048, F(o_kva), 0, nullptr, TT, 576, 576, nullptr, nullptr, nullptr);

  rms_k<true><<<TT, 256, 0, stream>>>(F(o_qlat), 512, 512, q_a_norm, W(o_qn), PLqn);
  rms_k<true><<<TT, 256, 0, stream>>>(F(o_kva), 576, 512, kv_a_norm, W(o_kvn), PLqn);

  // q_b / kv_b projections (split in, split out)
  transpose_cvt<true><<<dim3(96, 16, 1), 256, 0, stream>>>(w_q_b, W(o_scr), 512, 3072, 3072);
  gemm128<E_SPLIT, false, true><<<dim3(16, 24), 256, 0, stream>>>(W(o_qn), 512, PLqn, W(o_scr), PLwqb, 0, 512, W(o_qbig), PLqb, nullptr, TT, 3072, 3072, nullptr, nullptr, nullptr);
  transpose_cvt<true><<<dim3(128, 16, 1), 256, 0, stream>>>(w_kv_b, W(o_scr), 512, 4096, 4096);
  gemm128<E_SPLIT, false, true><<<dim3(16, 32), 256, 0, stream>>>(W(o_kvn), 512, PLqn, W(o_scr), PLwkvb, 0, 512, W(o_kvbig), PLkvb, nullptr, TT, 4096, 4096, nullptr, nullptr, nullptr);

  rope_pack<<<TT, 256, 0, stream>>>(W(o_qbig), PLqb, W(o_kvbig), PLkvb, F(o_kva), W(o_qf), W(o_kf), PLf, W(o_vv), PLv);

  attn_k<<<dim3(16, 32), 256, 0, stream>>>(W(o_qf), W(o_kf), PLf, W(o_vv), PLv, W(o_ao), PLao);

  // out = ao @ w_out + x   (split precision; out doubles as residual h)
  transpose_cvt<true><<<dim3(64, 64, 1), 256, 0, stream>>>(w_out, W(o_scr), 2048, 2048, 2048);
  gemm128<E_ADDSRC, false, true><<<dim3(16, 16), 256, 0, stream>>>(W(o_ao), 2048, PLao, W(o_scr), PLwout, 0, 2048, out, 0, x, TT, 2048, 2048, nullptr, nullptr, nullptr);

  rms_k<false><<<TT, 256, 0, stream>>>(out, 2048, 2048, norm2_w, W(o_xt), 0);

  route1<<<TT, 256, 0, stream>>>(out, norm2_w, gate_w, gate_b, F(o_wcomb), I(o_gmask), I(o_cnt));
  route2<<<1, 64, 0, stream>>>(I(o_cnt), I(o_offs));
  route3<<<TT / 256, 256, 0, stream>>>(F(o_wcomb), I(o_gmask), I(o_offs), I(o_fill), I(o_tok), F(o_wof), I(o_slot));

  // shared FFN (plain bf16): acts = silu(xt@ws_gate)*(xt@ws_up); out += acts @ ws_down
  transpose_cvt<false><<<dim3(16, 64, 1), 256, 0, stream>>>(ws_gate, W(o_scr), 2048, 512, 512);
  transpose_cvt<false><<<dim3(16, 64, 1), 256, 0, stream>>>(ws_up, W(o_scr2), 2048, 512, 512);
  ffn_act<false><<<dim3(16, 8, 1), 256, 0, stream>>>(W(o_xt), W(o_scr), W(o_scr2), 0, W(o_acts), nullptr, nullptr, nullptr, TT);
  transpose_cvt<false><<<dim3(64, 16, 1), 256, 0, stream>>>(ws_down, W(o_scr), 512, 2048, 2048);
  gemm128<E_ADDINTO, false, false><<<dim3(16, 16), 256, 0, stream>>>(W(o_acts), 512, 0, W(o_scr), 0, 0, 512, out, 0, nullptr, TT, 2048, 2048, nullptr, nullptr, nullptr);

  // expert FFN (grouped, plain bf16): act = silu(g)*u; eo[slot] = (act @ w_down[e]) * w_slot
  transpose_cvt<false><<<dim3(16, 64, 16), 256, 0, stream>>>(w_gate, W(o_Wg), 2048, 512, 512);
  transpose_cvt<false><<<dim3(16, 64, 16), 256, 0, stream>>>(w_up, W(o_Wu), 2048, 512, 512);
  ffn_act<true><<<dim3(32, 8, 16), 256, 0, stream>>>(W(o_xt), W(o_Wg), W(o_Wu), (size_t)512 * 2048, W(o_act), I(o_cnt), I(o_offs), I(o_tok), 0);
  transpose_cvt<false><<<dim3(64, 16, 16), 256, 0, stream>>>(w_down, W(o_Wd2), 512, 2048, 2048);
  gemm128<E_BF16SC, true, false><<<dim3(32, 16, 16), 256, 0, stream>>>(W(o_act), 512, 0, W(o_Wd2), 0, (size_t)2048 * 512, 512, W(o_eo), 0, nullptr, 0, 2048, 2048, I(o_cnt), I(o_offs), F(o_wof));

  // out[t] += sum of this token's 8 expert rows
  finalk<<<TT, 256, 0, stream>>>(W(o_eo), I(o_slot), out);
}

// Round 8
// 1769.370 us; speedup vs baseline: 1.1138x; 1.0150x over previous
//
#include <hip/hip_runtime.h>
#include <hip/hip_bf16.h>

typedef __attribute__((ext_vector_type(8))) __bf16 bf16x8;
typedef __attribute__((ext_vector_type(4))) float f32x4;
typedef __hip_bfloat16 bf16;

#define DEV __device__ __forceinline__

constexpr int TT = 2048;      // B*S tokens
constexpr int NSLOT = 16384;  // TT * TOPK(8)

DEV void gl_lds16(const void* g, void* l) {
  __builtin_amdgcn_global_load_lds((const __attribute__((address_space(1))) unsigned int*)g,
                                   (__attribute__((address_space(3))) unsigned int*)l, 16, 0, 0);
}

DEV bf16 cvt(float v) { return __float2bfloat16(v); }

// ---------------- transpose + convert: dst[c][r] = src[r][c] split hi/lo, rows padded to Cpad (zero fill)
template <bool SPLIT>
__global__ __launch_bounds__(256) void transpose_cvt(const float* __restrict__ src, bf16* __restrict__ dst,
                                                     int R, int C, int Cpad) {
  int e = blockIdx.z;  // SPLIT calls always use gridDim.z == 1
  src += (size_t)e * R * C;
  dst += (size_t)e * Cpad * R;
  size_t pl = (size_t)Cpad * R;  // lo plane offset (elements)
  __shared__ float t[32][33];
  int c0 = blockIdx.x * 32, r0 = blockIdx.y * 32;
  int tx = threadIdx.x & 31, ty = threadIdx.x >> 5;
#pragma unroll
  for (int i = 0; i < 4; ++i) {
    int r = ty + i * 8;
    int cc = c0 + tx;
    float v = (cc < C) ? src[(size_t)(r0 + r) * C + cc] : 0.f;
    t[r][tx] = v;
  }
  __syncthreads();
#pragma unroll
  for (int i = 0; i < 4; ++i) {
    int c = ty + i * 8;
    float v = t[tx][c];
    size_t idx = (size_t)(c0 + c) * R + (r0 + tx);
    bf16 hi = cvt(v);
    dst[idx] = hi;
    if (SPLIT) dst[pl + idx] = cvt(v - (float)hi);
  }
}

// ---------------- RMSNorm: dst = src*rsqrt(mean(src^2)+eps)*w, optional hi/lo split output
template <bool SPLIT>
__global__ __launch_bounds__(256) void rms_k(const float* __restrict__ src, int sst, int C,
                                             const float* __restrict__ wgt, bf16* __restrict__ dst,
                                             size_t dstPl) {
  int t = blockIdx.x;
  const float* sp = src + (size_t)t * sst;
  bf16* dp = dst + (size_t)t * C;
  int n4 = C >> 2;
  float ss = 0.f;
  for (int i = threadIdx.x; i < n4; i += 256) {
    float4 v = ((const float4*)sp)[i];
    ss += v.x * v.x + v.y * v.y + v.z * v.z + v.w * v.w;
  }
#pragma unroll
  for (int d = 1; d < 64; d <<= 1) ss += __shfl_xor(ss, d, 64);
  __shared__ float part[4];
  if ((threadIdx.x & 63) == 0) part[threadIdx.x >> 6] = ss;
  __syncthreads();
  float rinv = rsqrtf((part[0] + part[1] + part[2] + part[3]) / (float)C + 1e-6f);
  for (int i = threadIdx.x; i < n4; i += 256) {
    float4 v = ((const float4*)sp)[i];
    float4 g = ((const float4*)wgt)[i];
    float y[4] = {v.x * rinv * g.x, v.y * rinv * g.y, v.z * rinv * g.z, v.w * rinv * g.w};
    union { bf16 h[4]; short4 s; } uh, ul;
#pragma unroll
    for (int j = 0; j < 4; ++j) {
      bf16 hi = cvt(y[j]);
      uh.h[j] = hi;
      ul.h[j] = cvt(y[j] - (float)hi);
    }
    ((short4*)dp)[i] = uh.s;
    if (SPLIT) ((short4*)(dp + dstPl))[i] = ul.s;
  }
}

// ---------------- generic 128x128 bf16 GEMM, C = A[M,K] * WT[N,K]^T, optional split-bf16 precision
enum { E_F32 = 0, E_ADDSRC = 1, E_ADDINTO = 2, E_SPLIT = 3, E_BF16SC = 4 };

template <int EPI, bool EXPERT, bool SPLIT>
__global__ __launch_bounds__(256, SPLIT ? 2 : 4)
void gemm128(const bf16* __restrict__ A, int lda, size_t aPl,
             const bf16* __restrict__ WT, size_t bPl, size_t wtsE, int K,
             void* __restrict__ Cout, size_t cPl, const float* __restrict__ SRC,
             int M, int N, int ldc,
             const int* __restrict__ cnt, const int* __restrict__ offs,
             const float* __restrict__ rowscale) {
  int e = EXPERT ? blockIdx.z : 0;
  int Mloc = EXPERT ? cnt[e] : M;
  int m0 = blockIdx.x * 128;
  if (EXPERT && m0 >= Mloc) return;
  int rowbase = EXPERT ? offs[e] : 0;
  const bf16* Ae = A + (size_t)rowbase * lda;
  const bf16* We = WT + (EXPERT ? (size_t)e * wtsE : 0);
  int n0 = blockIdx.y * 128;

  __shared__ __align__(16) bf16 Ab[(SPLIT ? 2 : 1) * 128 * 64];
  __shared__ __align__(16) bf16 Bb[(SPLIT ? 2 : 1) * 128 * 64];

  int tid = threadIdx.x, w = tid >> 6, l = tid & 63;
  int wr = w >> 1, wc = w & 1;
  int fe = w * 512 + l * 8, sr = fe >> 6, sk = fe & 63;

  f32x4 acc[4][4];
#pragma unroll
  for (int i = 0; i < 4; ++i)
#pragma unroll
    for (int j = 0; j < 4; ++j) acc[i][j] = (f32x4){0.f, 0.f, 0.f, 0.f};

  for (int k0 = 0; k0 < K; k0 += 64) {
    __syncthreads();
#pragma unroll
    for (int c = 0; c < 4; ++c) {
      int r = c * 32 + sr;
      gl_lds16(Ae + (size_t)(m0 + r) * lda + (k0 + sk), &Ab[c * 2048 + w * 512]);
      gl_lds16(We + (size_t)(n0 + r) * K + (k0 + sk), &Bb[c * 2048 + w * 512]);
      if (SPLIT) {
        gl_lds16(Ae + aPl + (size_t)(m0 + r) * lda + (k0 + sk), &Ab[8192 + c * 2048 + w * 512]);
        gl_lds16(We + bPl + (size_t)(n0 + r) * K + (k0 + sk), &Bb[8192 + c * 2048 + w * 512]);
      }
    }
    __syncthreads();
#pragma unroll
    for (int kc = 0; kc < 2; ++kc) {
      bf16x8 af[4], bq[4], afl[4], bql[4];
#pragma unroll
      for (int m = 0; m < 4; ++m) {
        int o = (wr * 64 + m * 16 + (l & 15)) * 64 + kc * 32 + ((l >> 4) << 3);
        af[m] = *(const bf16x8*)&Ab[o];
        if (SPLIT) afl[m] = *(const bf16x8*)&Ab[8192 + o];
      }
#pragma unroll
      for (int n = 0; n < 4; ++n) {
        int o = (wc * 64 + n * 16 + (l & 15)) * 64 + kc * 32 + ((l >> 4) << 3);
        bq[n] = *(const bf16x8*)&Bb[o];
        if (SPLIT) bql[n] = *(const bf16x8*)&Bb[8192 + o];
      }
#pragma unroll
      for (int m = 0; m < 4; ++m)
#pragma unroll
        for (int n = 0; n < 4; ++n)
          acc[m][n] = __builtin_amdgcn_mfma_f32_16x16x32_bf16(af[m], bq[n], acc[m][n], 0, 0, 0);
      if (SPLIT) {
#pragma unroll
        for (int m = 0; m < 4; ++m)
#pragma unroll
          for (int n = 0; n < 4; ++n)
            acc[m][n] = __builtin_amdgcn_mfma_f32_16x16x32_bf16(afl[m], bq[n], acc[m][n], 0, 0, 0);
#pragma unroll
        for (int m = 0; m < 4; ++m)
#pragma unroll
          for (int n = 0; n < 4; ++n)
            acc[m][n] = __builtin_amdgcn_mfma_f32_16x16x32_bf16(af[m], bql[n], acc[m][n], 0, 0, 0);
      }
    }
  }

  int cb = n0 + wc * 64 + (l & 15);
  int rb = m0 + wr * 64 + ((l >> 4) << 2);
#pragma unroll
  for (int m = 0; m < 4; ++m) {
#pragma unroll
    for (int n = 0; n < 4; ++n) {
      int gc = cb + n * 16;
      if (gc >= N) continue;
#pragma unroll
      for (int j = 0; j < 4; ++j) {
        int grl = rb + m * 16 + j;
        if (EXPERT && grl >= Mloc) continue;
        size_t gr = (size_t)(rowbase + grl);
        float v = acc[m][n][j];
        if (EPI == E_F32) ((float*)Cout)[gr * ldc + gc] = v;
        else if (EPI == E_ADDSRC) ((float*)Cout)[gr * ldc + gc] = v + SRC[gr * ldc + gc];
        else if (EPI == E_ADDINTO) ((float*)Cout)[gr * ldc + gc] += v;
        else if (EPI == E_SPLIT) {
          bf16 hi = cvt(v);
          ((bf16*)Cout)[gr * ldc + gc] = hi;
          ((bf16*)Cout)[cPl + gr * ldc + gc] = cvt(v - (float)hi);
        } else {  // E_BF16SC: eo[slot] = bf16(v * w_slot)
          ((bf16*)Cout)[gr * ldc + gc] = cvt(v * rowscale[gr]);
        }
      }
    }
  }
}

// ---------------- fused gate/up GEMM + silu*mul -> bf16 act. Tiles 128 rows x 64 im. (plain bf16)
template <bool GATHER>
__global__ __launch_bounds__(256, 4)
void ffn_act(const bf16* __restrict__ X,
             const bf16* __restrict__ WTg, const bf16* __restrict__ WTu, size_t wtsE,
             bf16* __restrict__ Out,
             const int* __restrict__ cnt, const int* __restrict__ offs,
             const int* __restrict__ tok_of, int M) {
  int e = GATHER ? blockIdx.z : 0;
  int Mloc = GATHER ? cnt[e] : M;
  int m0 = blockIdx.x * 128;
  if (m0 >= Mloc) return;
  int rowbase = GATHER ? offs[e] : 0;
  int n0 = blockIdx.y * 64;
  const bf16* Wg = WTg + (size_t)e * wtsE;
  const bf16* Wu = WTu + (size_t)e * wtsE;

  __shared__ __align__(16) bf16 Ab[128 * 64];
  __shared__ __align__(16) bf16 Bg[64 * 64];
  __shared__ __align__(16) bf16 Bu[64 * 64];

  int tid = threadIdx.x, w = tid >> 6, l = tid & 63;
  int fe = w * 512 + l * 8, sr = fe >> 6, sk = fe & 63;

  f32x4 ag[2][4], au[2][4];
#pragma unroll
  for (int i = 0; i < 2; ++i)
#pragma unroll
    for (int j = 0; j < 4; ++j) { ag[i][j] = (f32x4){0.f,0.f,0.f,0.f}; au[i][j] = (f32x4){0.f,0.f,0.f,0.f}; }

  for (int k0 = 0; k0 < 2048; k0 += 64) {
    __syncthreads();
#pragma unroll
    for (int c = 0; c < 4; ++c) {
      int r = c * 32 + sr;
      int tok;
      if (GATHER) {
        int slot = rowbase + m0 + r;
        slot = slot < NSLOT ? slot : NSLOT - 1;
        tok = tok_of[slot];
      } else tok = m0 + r;
      gl_lds16(X + (size_t)tok * 2048 + (k0 + sk), &Ab[c * 2048 + w * 512]);
    }
#pragma unroll
    for (int c = 0; c < 2; ++c) {
      int r = c * 32 + sr;
      gl_lds16(Wg + (size_t)(n0 + r) * 2048 + (k0 + sk), &Bg[c * 2048 + w * 512]);
      gl_lds16(Wu + (size_t)(n0 + r) * 2048 + (k0 + sk), &Bu[c * 2048 + w * 512]);
    }
    __syncthreads();
#pragma unroll
    for (int kc = 0; kc < 2; ++kc) {
      bf16x8 a[2], bg[4], bu[4];
#pragma unroll
      for (int m = 0; m < 2; ++m)
        a[m] = *(const bf16x8*)&Ab[(w * 32 + m * 16 + (l & 15)) * 64 + kc * 32 + ((l >> 4) << 3)];
#pragma unroll
      for (int n = 0; n < 4; ++n) {
        bg[n] = *(const bf16x8*)&Bg[(n * 16 + (l & 15)) * 64 + kc * 32 + ((l >> 4) << 3)];
        bu[n] = *(const bf16x8*)&Bu[(n * 16 + (l & 15)) * 64 + kc * 32 + ((l >> 4) << 3)];
      }
#pragma unroll
      for (int m = 0; m < 2; ++m)
#pragma unroll
        for (int n = 0; n < 4; ++n) {
          ag[m][n] = __builtin_amdgcn_mfma_f32_16x16x32_bf16(a[m], bg[n], ag[m][n], 0, 0, 0);
          au[m][n] = __builtin_amdgcn_mfma_f32_16x16x32_bf16(a[m], bu[n], au[m][n], 0, 0, 0);
        }
    }
  }
  int cb = n0 + (l & 15);
  int rb = m0 + w * 32 + ((l >> 4) << 2);
#pragma unroll
  for (int m = 0; m < 2; ++m)
#pragma unroll
    for (int n = 0; n < 4; ++n)
#pragma unroll
      for (int j = 0; j < 4; ++j) {
        int grl = rb + m * 16 + j;
        if (grl >= Mloc) continue;
        float g = ag[m][n][j], u = au[m][n][j];
        float s = g / (1.f + __expf(-g)) * u;
        Out[(size_t)(rowbase + grl) * 512 + (cb + n * 16)] = __float2bfloat16(s);
      }
}

// ---------------- RoPE + repack q/kv (split hi/lo in and out)
__global__ __launch_bounds__(256) void rope_pack(const bf16* __restrict__ q, size_t qPl,
                                                 const bf16* __restrict__ kv, size_t kvPl,
                                                 const float* __restrict__ kva,
                                                 bf16* __restrict__ qf, bf16* __restrict__ kf, size_t fPl,
                                                 bf16* __restrict__ vvp, size_t vPl) {
  int t = blockIdx.x;
  int b = t >> 10, s = t & 1023;
  int tid = threadIdx.x;
  __shared__ float cs[64], sn[64], kr[64];
  if (tid < 64) {
    int i2 = tid & 31;
    float invf = (float)pow(10000.0, -(double)i2 / 32.0);  // == np fp32 inv_freq (correctly rounded)
    float fr = (float)s * invf;                            // np outer: single fp32 rounding
    cs[tid] = (float)cos((double)fr);                      // correctly-rounded cosf == np.cos
    sn[tid] = (float)sin((double)fr);
  }
  __syncthreads();
  if (tid < 64) {
    const float* kp = kva + (size_t)t * 576 + 512;
    float xv = kp[tid];
    float rh = (tid & 1) ? kp[tid - 1] : -kp[tid + 1];
    kr[tid] = xv * cs[tid] + rh * sn[tid];
  }
  __syncthreads();
  const bf16* qb = q + (size_t)t * 3072;
  const bf16* kvb = kv + (size_t)t * 4096;
  for (int idx = tid; idx < 16 * 192; idx += 256) {
    int hh = idx / 192, d = idx - hh * 192;
    size_t ob = ((size_t)(b * 16 + hh) * 1024 + s) * 192 + d;
    const bf16* qr = qb + hh * 192;
    float qv;
    if (d < 128) qv = (float)qr[d] + (float)qr[qPl + d];
    else {
      int dd = d - 128;
      float xv = (float)qr[128 + dd] + (float)qr[qPl + 128 + dd];
      float rh;
      if (dd & 1) rh = (float)qr[128 + dd - 1] + (float)qr[qPl + 128 + dd - 1];
      else rh = -((float)qr[128 + dd + 1] + (float)qr[qPl + 128 + dd + 1]);
      qv = xv * cs[dd] + rh * sn[dd];
    }
    bf16 qh = cvt(qv);
    qf[ob] = qh;
    qf[fPl + ob] = cvt(qv - (float)qh);
    float kvv;
    if (d < 128) kvv = (float)kvb[hh * 256 + d] + (float)kvb[kvPl + hh * 256 + d];
    else kvv = kr[d - 128];
    bf16 kh = cvt(kvv);
    kf[ob] = kh;
    kf[fPl + ob] = cvt(kvv - (float)kh);
  }
  for (int idx = tid; idx < 16 * 128; idx += 256) {
    int hh = idx >> 7, d = idx & 127;
    size_t ov = ((size_t)(b * 16 + hh) * 1024 + s) * 128 + d;
    float v = (float)kvb[hh * 256 + 128 + d] + (float)kvb[kvPl + hh * 256 + 128 + d];
    bf16 vh = cvt(v);
    vvp[ov] = vh;
    vvp[vPl + ov] = cvt(v - (float)vh);
  }
}

// ---------------- causal flash attention, split-bf16 precision, 64-row Q tiles, 4 waves x 16 rows
__global__ __launch_bounds__(256, 1)
void attn_k(const bf16* __restrict__ qf, const bf16* __restrict__ kf, size_t fPl,
            const bf16* __restrict__ vv, size_t vPl, bf16* __restrict__ ao, size_t aoPl) {
  int qt = blockIdx.x;
  int bh = blockIdx.y;
  int b = bh >> 4, h = bh & 15;
  int tid = threadIdx.x, w = tid >> 6, l = tid & 63;
  size_t base192 = (size_t)bh * 1024 * 192;
  size_t base128 = (size_t)bh * 1024 * 128;

  __shared__ __align__(16) bf16 Kt[2 * 64 * 200];
  __shared__ __align__(16) bf16 Vt[2 * 128 * 72];
  __shared__ __align__(16) bf16 Pt[2][4][16 * 72];

  bf16x8 aqh[6], aql[6];
  {
    const bf16* qp = qf + base192 + (size_t)(qt * 64 + w * 16 + (l & 15)) * 192 + ((l >> 4) << 3);
#pragma unroll
    for (int kc = 0; kc < 6; ++kc) {
      aqh[kc] = *(const bf16x8*)(qp + kc * 32);
      aql[kc] = *(const bf16x8*)(qp + fPl + kc * 32);
    }
  }
  f32x4 o[8];
#pragma unroll
  for (int i = 0; i < 8; ++i) o[i] = (f32x4){0.f, 0.f, 0.f, 0.f};
  float m_[4], s_[4];
#pragma unroll
  for (int j = 0; j < 4; ++j) { m_[j] = -3e38f; s_[j] = 0.f; }
  const float rs = 0.0721687836f;  // 1/sqrt(192)
  int qrow0 = qt * 64 + w * 16 + ((l >> 4) << 2);

  for (int kt = 0; kt <= qt; ++kt) {
    __syncthreads();
#pragma unroll
    for (int p = 0; p < 2; ++p) {
#pragma unroll
      for (int i = 0; i < 6; ++i) {
        int chunk = i * 256 + tid;
        int r = chunk / 24, cc = (chunk - r * 24) * 8;
        *(bf16x8*)&Kt[p * 12800 + r * 200 + cc] =
            *(const bf16x8*)(kf + p * fPl + base192 + (size_t)(kt * 64 + r) * 192 + cc);
      }
#pragma unroll
      for (int i = 0; i < 4; ++i) {
        int chunk = i * 256 + tid;
        int r = chunk >> 4, cc = (chunk & 15) * 8;
        bf16x8 vd = *(const bf16x8*)(vv + p * vPl + base128 + (size_t)(kt * 64 + r) * 128 + cc);
#pragma unroll
        for (int j = 0; j < 8; ++j) Vt[p * 9216 + (cc + j) * 72 + r] = *((const bf16*)&vd + j);
      }
    }
    __syncthreads();

    f32x4 sc[4];
#pragma unroll
    for (int nt = 0; nt < 4; ++nt) {
      sc[nt] = (f32x4){0.f, 0.f, 0.f, 0.f};
#pragma unroll
      for (int kc = 0; kc < 6; ++kc) {
        int ko = (nt * 16 + (l & 15)) * 200 + kc * 32 + ((l >> 4) << 3);
        bf16x8 bkh = *(const bf16x8*)&Kt[ko];
        bf16x8 bkl = *(const bf16x8*)&Kt[12800 + ko];
        sc[nt] = __builtin_amdgcn_mfma_f32_16x16x32_bf16(aqh[kc], bkh, sc[nt], 0, 0, 0);
        sc[nt] = __builtin_amdgcn_mfma_f32_16x16x32_bf16(aql[kc], bkh, sc[nt], 0, 0, 0);
        sc[nt] = __builtin_amdgcn_mfma_f32_16x16x32_bf16(aqh[kc], bkl, sc[nt], 0, 0, 0);
      }
    }
#pragma unroll
    for (int nt = 0; nt < 4; ++nt) {
      int kcol = kt * 64 + nt * 16 + (l & 15);
#pragma unroll
      for (int j = 0; j < 4; ++j) {
        float xv = sc[nt][j] * rs;
        if (kt == qt && kcol > qrow0 + j) xv = -1e30f;
        sc[nt][j] = xv;
      }
    }
#pragma unroll
    for (int j = 0; j < 4; ++j) {
      float mm = fmaxf(fmaxf(sc[0][j], sc[1][j]), fmaxf(sc[2][j], sc[3][j]));
#pragma unroll
      for (int d = 1; d < 16; d <<= 1) mm = fmaxf(mm, __shfl_xor(mm, d, 64));
      float mnew = fmaxf(m_[j], mm);
      float f = __expf(m_[j] - mnew);
      float ps = 0.f;
#pragma unroll
      for (int nt = 0; nt < 4; ++nt) {
        float p = __expf(sc[nt][j] - mnew);
        sc[nt][j] = p;
        ps += p;
      }
#pragma unroll
      for (int d = 1; d < 16; d <<= 1) ps += __shfl_xor(ps, d, 64);
      s_[j] = s_[j] * f + ps;
      m_[j] = mnew;
#pragma unroll
      for (int nt = 0; nt < 8; ++nt) o[nt][j] *= f;
    }
#pragma unroll
    for (int nt = 0; nt < 4; ++nt)
#pragma unroll
      for (int j = 0; j < 4; ++j) {
        float p = sc[nt][j];
        bf16 ph = cvt(p);
        int po = (((l >> 4) << 2) + j) * 72 + nt * 16 + (l & 15);
        Pt[0][w][po] = ph;
        Pt[1][w][po] = cvt(p - (float)ph);
      }
#pragma unroll
    for (int kc = 0; kc < 2; ++kc) {
      int pofs = (l & 15) * 72 + kc * 32 + ((l >> 4) << 3);
      bf16x8 aph = *(const bf16x8*)&Pt[0][w][pofs];
      bf16x8 apl = *(const bf16x8*)&Pt[1][w][pofs];
#pragma unroll
      for (int nt = 0; nt < 8; ++nt) {
        int vo = (nt * 16 + (l & 15)) * 72 + kc * 32 + ((l >> 4) << 3);
        bf16x8 bvh = *(const bf16x8*)&Vt[vo];
        bf16x8 bvl = *(const bf16x8*)&Vt[9216 + vo];
        o[nt] = __builtin_amdgcn_mfma_f32_16x16x32_bf16(aph, bvh, o[nt], 0, 0, 0);
        o[nt] = __builtin_amdgcn_mfma_f32_16x16x32_bf16(apl, bvh, o[nt], 0, 0, 0);
        o[nt] = __builtin_amdgcn_mfma_f32_16x16x32_bf16(aph, bvl, o[nt], 0, 0, 0);
      }
    }
  }
#pragma unroll
  for (int nt = 0; nt < 8; ++nt)
#pragma unroll
    for (int j = 0; j < 4; ++j) {
      size_t trow = (size_t)(b * 1024 + qrow0 + j);
      float v = o[nt][j] / s_[j];
      bf16 vh = cvt(v);
      size_t oi = trow * 2048 + h * 128 + nt * 16 + (l & 15);
      ao[oi] = vh;
      ao[aoPl + oi] = cvt(v - (float)vh);
    }
}

// ---------------- routing from fp32 h (re-does norm2 in fp32 so top-k decisions match reference)
__global__ __launch_bounds__(256) void route1(const float* __restrict__ h, const float* __restrict__ n2w,
                                              const float* __restrict__ gw, const float* __restrict__ gbias,
                                              float* __restrict__ wcomb, int* __restrict__ gmask,
                                              int* __restrict__ cnt) {
  int t = blockIdx.x;
  int tid = threadIdx.x, w = tid >> 6, l = tid & 63;
  const float* hp = h + (size_t)t * 2048;
  __shared__ float xr[2048];
  __shared__ float part[4];
  __shared__ float scs[16];
  float ss = 0.f;
  for (int i = tid; i < 512; i += 256) {
    float4 v = ((const float4*)hp)[i];
    ss += v.x * v.x + v.y * v.y + v.z * v.z + v.w * v.w;
  }
#pragma unroll
  for (int d = 1; d < 64; d <<= 1) ss += __shfl_xor(ss, d, 64);
  if (l == 0) part[w] = ss;
  __syncthreads();
  float rinv = rsqrtf((part[0] + part[1] + part[2] + part[3]) / 2048.f + 1e-6f);
  for (int i = tid; i < 512; i += 256) {
    float4 v = ((const float4*)hp)[i];
    float4 g = ((const float4*)n2w)[i];
    xr[i * 4 + 0] = v.x * rinv * g.x;
    xr[i * 4 + 1] = v.y * rinv * g.y;
    xr[i * 4 + 2] = v.z * rinv * g.z;
    xr[i * 4 + 3] = v.w * rinv * g.w;
  }
  __syncthreads();
#pragma unroll
  for (int ee = 0; ee < 4; ++ee) {
    int e = w * 4 + ee;
    float s = 0.f;
    for (int k = l; k < 2048; k += 64) s += xr[k] * gw[e * 2048 + k];
#pragma unroll
    for (int d = 1; d < 64; d <<= 1) s += __shfl_xor(s, d, 64);
    if (l == 0) scs[e] = 1.f / (1.f + expf(-s));
  }
  __syncthreads();
  if (tid == 0) {
    float scb[16];
#pragma unroll
    for (int e2 = 0; e2 < 16; ++e2) scb[e2] = scs[e2] + gbias[e2];
    float gsc[8];
#pragma unroll
    for (int g = 0; g < 8; ++g) gsc[g] = scb[2 * g] + scb[2 * g + 1];
    int mask = 0;
    for (int it = 0; it < 4; ++it) {
      float best = -3e38f;
      int bg = 0;
      for (int g = 0; g < 8; ++g)
        if (!((mask >> g) & 1) && gsc[g] > best) { best = gsc[g]; bg = g; }
      mask |= 1 << bg;
    }
    float wv[16];
#pragma unroll
    for (int e2 = 0; e2 < 16; ++e2) wv[e2] = 0.f;
    float wsum = 0.f;
    for (int g = 0; g < 8; ++g)
      if ((mask >> g) & 1) {
        wv[2 * g] = scs[2 * g];
        wv[2 * g + 1] = scs[2 * g + 1];
        wsum += scs[2 * g] + scs[2 * g + 1];
        atomicAdd(&cnt[2 * g], 1);
        atomicAdd(&cnt[2 * g + 1], 1);
      }
    float inv = 2.5f / (wsum + 1e-20f);
#pragma unroll
    for (int e2 = 0; e2 < 16; ++e2) wcomb[t * 16 + e2] = wv[e2] * inv;
    gmask[t] = mask;
  }
}

__global__ void route2(const int* __restrict__ cnt, int* __restrict__ offs) {
  if (threadIdx.x == 0) {
    int a = 0;
    for (int e = 0; e < 16; ++e) { offs[e] = a; a += cnt[e]; }
  }
}

__global__ void route3(const float* __restrict__ wcomb, const int* __restrict__ gmask,
                       const int* __restrict__ offs, int* __restrict__ fill,
                       int* __restrict__ tok_of, float* __restrict__ w_of, int* __restrict__ slot_of) {
  int t = blockIdx.x * 256 + threadIdx.x;
  if (t >= TT) return;
  int mask = gmask[t];
  int j = 0;
  for (int g = 0; g < 8; ++g) {
    if (!((mask >> g) & 1)) continue;
    for (int p = 0; p < 2; ++p) {
      int e = 2 * g + p;
      int pos = atomicAdd(&fill[e], 1);
      int slot = offs[e] + pos;
      tok_of[slot] = t;
      w_of[slot] = wcomb[t * 16 + e];
      slot_of[t * 8 + j] = slot;
      ++j;
    }
  }
}

// ---------------- final: out[t] += sum of 8 pre-weighted expert rows (out already = h + shared)
__global__ __launch_bounds__(256) void finalk(const bf16* __restrict__ eo,
                                              const int* __restrict__ slot_of, float* __restrict__ out) {
  int t = blockIdx.x, tid = threadIdx.x;
  float* op = out + (size_t)t * 2048;
  float a[8];
  float4 h0 = ((const float4*)op)[tid * 2];
  float4 h1v = ((const float4*)op)[tid * 2 + 1];
  a[0] = h0.x; a[1] = h0.y; a[2] = h0.z; a[3] = h0.w;
  a[4] = h1v.x; a[5] = h1v.y; a[6] = h1v.z; a[7] = h1v.w;
#pragma unroll
  for (int j = 0; j < 8; ++j) {
    int slot = slot_of[t * 8 + j];
    bf16x8 v = ((const bf16x8*)(eo + (size_t)slot * 2048))[tid];
#pragma unroll
    for (int i = 0; i < 8; ++i) a[i] += (float)v[i];
  }
  ((float4*)op)[tid * 2] = make_float4(a[0], a[1], a[2], a[3]);
  ((float4*)op)[tid * 2 + 1] = make_float4(a[4], a[5], a[6], a[7]);
}

extern "C" void kernel_launch(void* const* d_in, const int* in_sizes, int n_in,
                              void* d_out, int out_size, void* d_ws, size_t ws_size,
                              hipStream_t stream) {
  (void)in_sizes; (void)n_in; (void)out_size; (void)ws_size;
  const float* x        = (const float*)d_in[0];
  const float* norm1_w  = (const float*)d_in[1];
  const float* w_q_a    = (const float*)d_in[2];
  const float* q_a_norm = (const float*)d_in[3];
  const float* w_q_b    = (const float*)d_in[4];
  const float* w_kv_a   = (const float*)d_in[5];
  const float* kv_a_norm= (const float*)d_in[6];
  const float* w_kv_b   = (const float*)d_in[7];
  const float* w_out    = (const float*)d_in[8];
  const float* norm2_w  = (const float*)d_in[9];
  const float* gate_w   = (const float*)d_in[10];
  const float* gate_b   = (const float*)d_in[11];
  const float* w_gate   = (const float*)d_in[12];
  const float* w_up     = (const float*)d_in[13];
  const float* w_down   = (const float*)d_in[14];
  const float* ws_gate  = (const float*)d_in[15];
  const float* ws_up    = (const float*)d_in[16];
  const float* ws_down  = (const float*)d_in[17];
  float* out = (float*)d_out;   // doubles as the fp32 residual h
  char* ws = (char*)d_ws;

  size_t cur = 0;
  auto al = [&](size_t b) { size_t o = cur; cur = (cur + b + 255) & ~(size_t)255; return o; };

  // --- dedicated (never overlaid) routing metadata
  size_t o_wcomb= al((size_t)TT * 16 * 4);
  size_t o_gmask= al((size_t)TT * 4);
  size_t o_cnt  = al(256);
  size_t o_fill = al(256);
  size_t o_offs = al(256);
  size_t o_tok  = al((size_t)(NSLOT + 128) * 4);
  size_t o_wof  = al((size_t)(NSLOT + 128) * 4);
  size_t o_slot = al((size_t)TT * 8 * 4);

  // --- big union region R1
  size_t r1 = cur;
  // phase1 (attention path; dead after attention / w_out gemm)
  size_t o_qlat = al((size_t)TT * 512 * 4);        // fp32
  size_t o_kva  = al((size_t)TT * 576 * 4);        // fp32 (lives until rope_pack)
  size_t o_qn   = al((size_t)TT * 512 * 2 * 2);    // hi/lo
  size_t o_kvn  = al((size_t)TT * 512 * 2 * 2);
  size_t o_qbig = al((size_t)TT * 3072 * 2 * 2);
  size_t o_kvbig= al((size_t)TT * 4096 * 2 * 2);
  size_t o_qf   = al((size_t)TT * 3072 * 2 * 2);
  size_t o_kf   = al((size_t)TT * 3072 * 2 * 2);
  size_t o_vv   = al((size_t)TT * 2048 * 2 * 2);
  size_t r1end = cur;
  // phase2 (MoE; all launches after attention). Reuse trick:
  //  - ffn_act reads Wg,Wu -> then w_down is transposed into the (dead) Wg slot
  //  - eo exactly occupies the (dead) Wu+Wd slots (33.55MB + 33.55MB = 67.1MB = NSLOT*2048*2)
  cur = r1;
  size_t o_Wg  = al((size_t)16 * 512 * 2048 * 2);   // later: Wd2 (transposed w_down)
  size_t o_Wu  = al((size_t)16 * 512 * 2048 * 2);   // later: eo (spans Wu+Wd slots)
  size_t o_Wd  = al((size_t)16 * 2048 * 512 * 2);
  size_t o_act  = al((size_t)(NSLOT + 128) * 512 * 2);
  size_t o_acts = al((size_t)TT * 512 * 2);
  if (cur < r1end) cur = r1end;
  size_t o_Wd2 = o_Wg;  // w_down transposed (after ffn_act done with Wg)
  size_t o_eo  = o_Wu;  // expert outputs (after ffn_act done with Wu; spans Wu+Wd)

  size_t o_h1 = al((size_t)TT * 2048 * 2 * 2);  // h1 hi/lo; reused as ao hi/lo after it dies
  size_t o_ao = o_h1;
  size_t o_xt = al((size_t)TT * 2048 * 2);
  size_t o_scr = al((size_t)2048 * 2048 * 2 * 2);  // transposed-weight scratch (max: w_out split)
  size_t o_scr2 = o_scr + (size_t)512 * 2048 * 2;  // second plain slot (ws_up)

  auto W = [&](size_t o) { return (bf16*)(ws + o); };
  auto F = [&](size_t o) { return (float*)(ws + o); };
  auto I = [&](size_t o) { return (int*)(ws + o); };

  // plane offsets (elements)
  const size_t PLh1 = (size_t)TT * 2048, PLqn = (size_t)TT * 512, PLqb = (size_t)TT * 3072,
               PLkvb = (size_t)TT * 4096, PLf = (size_t)TT * 3072, PLv = (size_t)TT * 2048,
               PLao = (size_t)TT * 2048;
  const size_t PLwqa = (size_t)512 * 2048, PLwkva = (size_t)640 * 2048, PLwqb = (size_t)3072 * 512,
               PLwkvb = (size_t)4096 * 512, PLwout = (size_t)2048 * 2048;

  hipMemsetAsync(ws + o_cnt, 0, 512, stream);  // cnt + fill

  rms_k<true><<<TT, 256, 0, stream>>>(x, 2048, 2048, norm1_w, W(o_h1), PLh1);

  // q_a / kv_a projections (split precision, fp32 out)
  transpose_cvt<true><<<dim3(16, 64, 1), 256, 0, stream>>>(w_q_a, W(o_scr), 2048, 512, 512);
  gemm128<E_F32, false, true><<<dim3(16, 4), 256, 0, stream>>>(W(o_h1), 2048, PLh1, W(o_scr), PLwqa, 0, 2048, F(o_qlat), 0, nullptr, TT, 512, 512, nullptr, nullptr, nullptr);
  transpose_cvt<true><<<dim3(20, 64, 1), 256, 0, stream>>>(w_kv_a, W(o_scr), 2048, 576, 640);
  gemm128<E_F32, false, true><<<dim3(16, 5), 256, 0, stream>>>(W(o_h1), 2048, PLh1, W(o_scr), PLwkva, 0, 2048, F(o_kva), 0, nullptr, TT, 576, 576, nullptr, nullptr, nullptr);

  rms_k<true><<<TT, 256, 0, stream>>>(F(o_qlat), 512, 512, q_a_norm, W(o_qn), PLqn);
  rms_k<true><<<TT, 256, 0, stream>>>(F(o_kva), 576, 512, kv_a_norm, W(o_kvn), PLqn);

  // q_b / kv_b projections (split in, split out)
  transpose_cvt<true><<<dim3(96, 16, 1), 256, 0, stream>>>(w_q_b, W(o_scr), 512, 3072, 3072);
  gemm128<E_SPLIT, false, true><<<dim3(16, 24), 256, 0, stream>>>(W(o_qn), 512, PLqn, W(o_scr), PLwqb, 0, 512, W(o_qbig), PLqb, nullptr, TT, 3072, 3072, nullptr, nullptr, nullptr);
  transpose_cvt<true><<<dim3(128, 16, 1), 256, 0, stream>>>(w_kv_b, W(o_scr), 512, 4096, 4096);
  gemm128<E_SPLIT, false, true><<<dim3(16, 32), 256, 0, stream>>>(W(o_kvn), 512, PLqn, W(o_scr), PLwkvb, 0, 512, W(o_kvbig), PLkvb, nullptr, TT, 4096, 4096, nullptr, nullptr, nullptr);

  rope_pack<<<TT, 256, 0, stream>>>(W(o_qbig), PLqb, W(o_kvbig), PLkvb, F(o_kva), W(o_qf), W(o_kf), PLf, W(o_vv), PLv);

  attn_k<<<dim3(16, 32), 256, 0, stream>>>(W(o_qf), W(o_kf), PLf, W(o_vv), PLv, W(o_ao), PLao);

  // out = ao @ w_out + x   (split precision; out doubles as residual h)
  transpose_cvt<true><<<dim3(64, 64, 1), 256, 0, stream>>>(w_out, W(o_scr), 2048, 2048, 2048);
  gemm128<E_ADDSRC, false, true><<<dim3(16, 16), 256, 0, stream>>>(W(o_ao), 2048, PLao, W(o_scr), PLwout, 0, 2048, out, 0, x, TT, 2048, 2048, nullptr, nullptr, nullptr);

  rms_k<false><<<TT, 256, 0, stream>>>(out, 2048, 2048, norm2_w, W(o_xt), 0);

  route1<<<TT, 256, 0, stream>>>(out, norm2_w, gate_w, gate_b, F(o_wcomb), I(o_gmask), I(o_cnt));
  route2<<<1, 64, 0, stream>>>(I(o_cnt), I(o_offs));
  route3<<<TT / 256, 256, 0, stream>>>(F(o_wcomb), I(o_gmask), I(o_offs), I(o_fill), I(o_tok), F(o_wof), I(o_slot));

  // shared FFN (plain bf16): acts = silu(xt@ws_gate)*(xt@ws_up); out += acts @ ws_down
  transpose_cvt<false><<<dim3(16, 64, 1), 256, 0, stream>>>(ws_gate, W(o_scr), 2048, 512, 512);
  transpose_cvt<false><<<dim3(16, 64, 1), 256, 0, stream>>>(ws_up, W(o_scr2), 2048, 512, 512);
  ffn_act<false><<<dim3(16, 8, 1), 256, 0, stream>>>(W(o_xt), W(o_scr), W(o_scr2), 0, W(o_acts), nullptr, nullptr, nullptr, TT);
  transpose_cvt<false><<<dim3(64, 16, 1), 256, 0, stream>>>(ws_down, W(o_scr), 512, 2048, 2048);
  gemm128<E_ADDINTO, false, false><<<dim3(16, 16), 256, 0, stream>>>(W(o_acts), 512, 0, W(o_scr), 0, 0, 512, out, 0, nullptr, TT, 2048, 2048, nullptr, nullptr, nullptr);

  // expert FFN (grouped, plain bf16): act = silu(g)*u; eo[slot] = (act @ w_down[e]) * w_slot
  transpose_cvt<false><<<dim3(16, 64, 16), 256, 0, stream>>>(w_gate, W(o_Wg), 2048, 512, 512);
  transpose_cvt<false><<<dim3(16, 64, 16), 256, 0, stream>>>(w_up, W(o_Wu), 2048, 512, 512);
  ffn_act<true><<<dim3(32, 8, 16), 256, 0, stream>>>(W(o_xt), W(o_Wg), W(o_Wu), (size_t)512 * 2048, W(o_act), I(o_cnt), I(o_offs), I(o_tok), 0);
  transpose_cvt<false><<<dim3(64, 16, 16), 256, 0, stream>>>(w_down, W(o_Wd2), 512, 2048, 2048);
  gemm128<E_BF16SC, true, false><<<dim3(32, 16, 16), 256, 0, stream>>>(W(o_act), 512, 0, W(o_Wd2), 0, (size_t)2048 * 512, 512, W(o_eo), 0, nullptr, 0, 2048, 2048, I(o_cnt), I(o_offs), F(o_wof));

  // out[t] += sum of this token's 8 expert rows
  finalk<<<TT, 256, 0, stream>>>(W(o_eo), I(o_slot), out);
}

// Round 10
// 1458.909 us; speedup vs baseline: 1.3508x; 1.2128x over previous
//
#include <hip/hip_runtime.h>
#include <hip/hip_bf16.h>

typedef __attribute__((ext_vector_type(8))) __bf16 bf16x8;
typedef __attribute__((ext_vector_type(4))) float f32x4;
typedef __hip_bfloat16 bf16;

#define DEV __device__ __forceinline__

constexpr int TT = 2048;      // B*S tokens
constexpr int NSLOT = 16384;  // TT * TOPK(8)

DEV void gl_lds16(const void* g, void* l) {
  __builtin_amdgcn_global_load_lds((const __attribute__((address_space(1))) unsigned int*)g,
                                   (__attribute__((address_space(3))) unsigned int*)l, 16, 0, 0);
}

DEV bf16 cvt(float v) { return __float2bfloat16(v); }

// ---------------- transpose + convert: dst[c][r] = src[r][c] split hi/lo, rows padded to Cpad (zero fill)
template <bool SPLIT>
__global__ __launch_bounds__(256) void transpose_cvt(const float* __restrict__ src, bf16* __restrict__ dst,
                                                     int R, int C, int Cpad) {
  int e = blockIdx.z;  // SPLIT calls always use gridDim.z == 1
  src += (size_t)e * R * C;
  dst += (size_t)e * Cpad * R;
  size_t pl = (size_t)Cpad * R;  // lo plane offset (elements)
  __shared__ float t[32][33];
  int c0 = blockIdx.x * 32, r0 = blockIdx.y * 32;
  int tx = threadIdx.x & 31, ty = threadIdx.x >> 5;
#pragma unroll
  for (int i = 0; i < 4; ++i) {
    int r = ty + i * 8;
    int cc = c0 + tx;
    float v = (cc < C) ? src[(size_t)(r0 + r) * C + cc] : 0.f;
    t[r][tx] = v;
  }
  __syncthreads();
#pragma unroll
  for (int i = 0; i < 4; ++i) {
    int c = ty + i * 8;
    float v = t[tx][c];
    size_t idx = (size_t)(c0 + c) * R + (r0 + tx);
    bf16 hi = cvt(v);
    dst[idx] = hi;
    if (SPLIT) dst[pl + idx] = cvt(v - (float)hi);
  }
}

// ---------------- RMSNorm: dst = src*rsqrt(mean(src^2)+eps)*w, optional hi/lo split output
template <bool SPLIT>
__global__ __launch_bounds__(256) void rms_k(const float* __restrict__ src, int sst, int C,
                                             const float* __restrict__ wgt, bf16* __restrict__ dst,
                                             size_t dstPl) {
  int t = blockIdx.x;
  const float* sp = src + (size_t)t * sst;
  bf16* dp = dst + (size_t)t * C;
  int n4 = C >> 2;
  float ss = 0.f;
  for (int i = threadIdx.x; i < n4; i += 256) {
    float4 v = ((const float4*)sp)[i];
    ss += v.x * v.x + v.y * v.y + v.z * v.z + v.w * v.w;
  }
#pragma unroll
  for (int d = 1; d < 64; d <<= 1) ss += __shfl_xor(ss, d, 64);
  __shared__ float part[4];
  if ((threadIdx.x & 63) == 0) part[threadIdx.x >> 6] = ss;
  __syncthreads();
  float rinv = rsqrtf((part[0] + part[1] + part[2] + part[3]) / (float)C + 1e-6f);
  for (int i = threadIdx.x; i < n4; i += 256) {
    float4 v = ((const float4*)sp)[i];
    float4 g = ((const float4*)wgt)[i];
    float y[4] = {v.x * rinv * g.x, v.y * rinv * g.y, v.z * rinv * g.z, v.w * rinv * g.w};
    union { bf16 h[4]; short4 s; } uh, ul;
#pragma unroll
    for (int j = 0; j < 4; ++j) {
      bf16 hi = cvt(y[j]);
      uh.h[j] = hi;
      ul.h[j] = cvt(y[j] - (float)hi);
    }
    ((short4*)dp)[i] = uh.s;
    if (SPLIT) ((short4*)(dp + dstPl))[i] = ul.s;
  }
}

// ---------------- generic 128x128 bf16 GEMM, C = A[M,K] * WT[N,K]^T, optional split-bf16 precision
// EXPERT grids are launched (n_tiles, E, m_tiles) so the early-exit m dimension is SLOWEST
// (avoids dispatch clustering: active blocks spread over all CUs).
enum { E_F32 = 0, E_ADDSRC = 1, E_ADDINTO = 2, E_SPLIT = 3, E_BF16SC = 4 };

template <int EPI, bool EXPERT, bool SPLIT>
__global__ __launch_bounds__(256, SPLIT ? 2 : 4)
void gemm128(const bf16* __restrict__ A, int lda, size_t aPl,
             const bf16* __restrict__ WT, size_t bPl, size_t wtsE, int K,
             void* __restrict__ Cout, size_t cPl, const float* __restrict__ SRC,
             int M, int N, int ldc,
             const int* __restrict__ cnt, const int* __restrict__ offs,
             const float* __restrict__ rowscale) {
  int e = EXPERT ? blockIdx.y : 0;
  int mb = EXPERT ? blockIdx.z : blockIdx.x;
  int nb = EXPERT ? blockIdx.x : blockIdx.y;
  int Mloc = EXPERT ? cnt[e] : M;
  int m0 = mb * 128;
  if (EXPERT && m0 >= Mloc) return;
  int rowbase = EXPERT ? offs[e] : 0;
  const bf16* Ae = A + (size_t)rowbase * lda;
  const bf16* We = WT + (EXPERT ? (size_t)e * wtsE : 0);
  int n0 = nb * 128;

  __shared__ __align__(16) bf16 Ab[(SPLIT ? 2 : 1) * 128 * 64];
  __shared__ __align__(16) bf16 Bb[(SPLIT ? 2 : 1) * 128 * 64];

  int tid = threadIdx.x, w = tid >> 6, l = tid & 63;
  int wr = w >> 1, wc = w & 1;
  int fe = w * 512 + l * 8, sr = fe >> 6, sk = fe & 63;

  f32x4 acc[4][4];
#pragma unroll
  for (int i = 0; i < 4; ++i)
#pragma unroll
    for (int j = 0; j < 4; ++j) acc[i][j] = (f32x4){0.f, 0.f, 0.f, 0.f};

  for (int k0 = 0; k0 < K; k0 += 64) {
    __syncthreads();
#pragma unroll
    for (int c = 0; c < 4; ++c) {
      int r = c * 32 + sr;
      gl_lds16(Ae + (size_t)(m0 + r) * lda + (k0 + sk), &Ab[c * 2048 + w * 512]);
      gl_lds16(We + (size_t)(n0 + r) * K + (k0 + sk), &Bb[c * 2048 + w * 512]);
      if (SPLIT) {
        gl_lds16(Ae + aPl + (size_t)(m0 + r) * lda + (k0 + sk), &Ab[8192 + c * 2048 + w * 512]);
        gl_lds16(We + bPl + (size_t)(n0 + r) * K + (k0 + sk), &Bb[8192 + c * 2048 + w * 512]);
      }
    }
    __syncthreads();
#pragma unroll
    for (int kc = 0; kc < 2; ++kc) {
      bf16x8 af[4], bq[4], afl[4], bql[4];
#pragma unroll
      for (int m = 0; m < 4; ++m) {
        int o = (wr * 64 + m * 16 + (l & 15)) * 64 + kc * 32 + ((l >> 4) << 3);
        af[m] = *(const bf16x8*)&Ab[o];
        if (SPLIT) afl[m] = *(const bf16x8*)&Ab[8192 + o];
      }
#pragma unroll
      for (int n = 0; n < 4; ++n) {
        int o = (wc * 64 + n * 16 + (l & 15)) * 64 + kc * 32 + ((l >> 4) << 3);
        bq[n] = *(const bf16x8*)&Bb[o];
        if (SPLIT) bql[n] = *(const bf16x8*)&Bb[8192 + o];
      }
#pragma unroll
      for (int m = 0; m < 4; ++m)
#pragma unroll
        for (int n = 0; n < 4; ++n)
          acc[m][n] = __builtin_amdgcn_mfma_f32_16x16x32_bf16(af[m], bq[n], acc[m][n], 0, 0, 0);
      if (SPLIT) {
#pragma unroll
        for (int m = 0; m < 4; ++m)
#pragma unroll
          for (int n = 0; n < 4; ++n)
            acc[m][n] = __builtin_amdgcn_mfma_f32_16x16x32_bf16(afl[m], bq[n], acc[m][n], 0, 0, 0);
#pragma unroll
        for (int m = 0; m < 4; ++m)
#pragma unroll
          for (int n = 0; n < 4; ++n)
            acc[m][n] = __builtin_amdgcn_mfma_f32_16x16x32_bf16(af[m], bql[n], acc[m][n], 0, 0, 0);
      }
    }
  }

  int cb = n0 + wc * 64 + (l & 15);
  int rb = m0 + wr * 64 + ((l >> 4) << 2);
#pragma unroll
  for (int m = 0; m < 4; ++m) {
#pragma unroll
    for (int n = 0; n < 4; ++n) {
      int gc = cb + n * 16;
      if (gc >= N) continue;
#pragma unroll
      for (int j = 0; j < 4; ++j) {
        int grl = rb + m * 16 + j;
        if (EXPERT && grl >= Mloc) continue;
        size_t gr = (size_t)(rowbase + grl);
        float v = acc[m][n][j];
        if (EPI == E_F32) ((float*)Cout)[gr * ldc + gc] = v;
        else if (EPI == E_ADDSRC) ((float*)Cout)[gr * ldc + gc] = v + SRC[gr * ldc + gc];
        else if (EPI == E_ADDINTO) ((float*)Cout)[gr * ldc + gc] += v;
        else if (EPI == E_SPLIT) {
          bf16 hi = cvt(v);
          ((bf16*)Cout)[gr * ldc + gc] = hi;
          ((bf16*)Cout)[cPl + gr * ldc + gc] = cvt(v - (float)hi);
        } else {  // E_BF16SC: eo[slot] = bf16(v * w_slot)
          ((bf16*)Cout)[gr * ldc + gc] = cvt(v * rowscale[gr]);
        }
      }
    }
  }
}

// ---------------- fused gate/up GEMM + silu*mul -> bf16 act. Tiles 128 rows x 64 im. (plain bf16)
// GATHER grids are launched (n_tiles, E, m_tiles); tok gather hoisted out of K-loop.
template <bool GATHER>
__global__ __launch_bounds__(256, 4)
void ffn_act(const bf16* __restrict__ X,
             const bf16* __restrict__ WTg, const bf16* __restrict__ WTu, size_t wtsE,
             bf16* __restrict__ Out,
             const int* __restrict__ cnt, const int* __restrict__ offs,
             const int* __restrict__ tok_of, int M) {
  int e = GATHER ? blockIdx.y : 0;
  int mb = GATHER ? blockIdx.z : blockIdx.x;
  int nb = GATHER ? blockIdx.x : blockIdx.y;
  int Mloc = GATHER ? cnt[e] : M;
  int m0 = mb * 128;
  if (m0 >= Mloc) return;
  int rowbase = GATHER ? offs[e] : 0;
  int n0 = nb * 64;
  const bf16* Wg = WTg + (size_t)e * wtsE;
  const bf16* Wu = WTu + (size_t)e * wtsE;

  __shared__ __align__(16) bf16 Ab[128 * 64];
  __shared__ __align__(16) bf16 Bg[64 * 64];
  __shared__ __align__(16) bf16 Bu[64 * 64];

  int tid = threadIdx.x, w = tid >> 6, l = tid & 63;
  int fe = w * 512 + l * 8, sr = fe >> 6, sk = fe & 63;

  // hoisted loop-invariant gather indices
  int tokc[4];
#pragma unroll
  for (int c = 0; c < 4; ++c) {
    int r = c * 32 + sr;
    if (GATHER) {
      int slot = rowbase + m0 + r;
      slot = slot < NSLOT ? slot : NSLOT - 1;
      tokc[c] = tok_of[slot];
    } else tokc[c] = m0 + r;
  }

  f32x4 ag[2][4], au[2][4];
#pragma unroll
  for (int i = 0; i < 2; ++i)
#pragma unroll
    for (int j = 0; j < 4; ++j) { ag[i][j] = (f32x4){0.f,0.f,0.f,0.f}; au[i][j] = (f32x4){0.f,0.f,0.f,0.f}; }

  for (int k0 = 0; k0 < 2048; k0 += 64) {
    __syncthreads();
#pragma unroll
    for (int c = 0; c < 4; ++c) {
      gl_lds16(X + (size_t)tokc[c] * 2048 + (k0 + sk), &Ab[c * 2048 + w * 512]);
    }
#pragma unroll
    for (int c = 0; c < 2; ++c) {
      int r = c * 32 + sr;
      gl_lds16(Wg + (size_t)(n0 + r) * 2048 + (k0 + sk), &Bg[c * 2048 + w * 512]);
      gl_lds16(Wu + (size_t)(n0 + r) * 2048 + (k0 + sk), &Bu[c * 2048 + w * 512]);
    }
    __syncthreads();
#pragma unroll
    for (int kc = 0; kc < 2; ++kc) {
      bf16x8 a[2], bg[4], bu[4];
#pragma unroll
      for (int m = 0; m < 2; ++m)
        a[m] = *(const bf16x8*)&Ab[(w * 32 + m * 16 + (l & 15)) * 64 + kc * 32 + ((l >> 4) << 3)];
#pragma unroll
      for (int n = 0; n < 4; ++n) {
        bg[n] = *(const bf16x8*)&Bg[(n * 16 + (l & 15)) * 64 + kc * 32 + ((l >> 4) << 3)];
        bu[n] = *(const bf16x8*)&Bu[(n * 16 + (l & 15)) * 64 + kc * 32 + ((l >> 4) << 3)];
      }
#pragma unroll
      for (int m = 0; m < 2; ++m)
#pragma unroll
        for (int n = 0; n < 4; ++n) {
          ag[m][n] = __builtin_amdgcn_mfma_f32_16x16x32_bf16(a[m], bg[n], ag[m][n], 0, 0, 0);
          au[m][n] = __builtin_amdgcn_mfma_f32_16x16x32_bf16(a[m], bu[n], au[m][n], 0, 0, 0);
        }
    }
  }
  int cb = n0 + (l & 15);
  int rb = m0 + w * 32 + ((l >> 4) << 2);
#pragma unroll
  for (int m = 0; m < 2; ++m)
#pragma unroll
    for (int n = 0; n < 4; ++n)
#pragma unroll
      for (int j = 0; j < 4; ++j) {
        int grl = rb + m * 16 + j;
        if (grl >= Mloc) continue;
        float g = ag[m][n][j], u = au[m][n][j];
        float s = g / (1.f + __expf(-g)) * u;
        Out[(size_t)(rowbase + grl) * 512 + (cb + n * 16)] = __float2bfloat16(s);
      }
}

// ---------------- RoPE + repack q/kv (split hi/lo in and out)
__global__ __launch_bounds__(256) void rope_pack(const bf16* __restrict__ q, size_t qPl,
                                                 const bf16* __restrict__ kv, size_t kvPl,
                                                 const float* __restrict__ kva,
                                                 bf16* __restrict__ qf, bf16* __restrict__ kf, size_t fPl,
                                                 bf16* __restrict__ vvp, size_t vPl) {
  int t = blockIdx.x;
  int b = t >> 10, s = t & 1023;
  int tid = threadIdx.x;
  __shared__ float cs[64], sn[64], kr[64];
  if (tid < 64) {
    int i2 = tid & 31;
    float invf = (float)pow(10000.0, -(double)i2 / 32.0);  // == np fp32 inv_freq (correctly rounded)
    float fr = (float)s * invf;                            // np outer: single fp32 rounding
    cs[tid] = (float)cos((double)fr);                      // correctly-rounded cosf == np.cos
    sn[tid] = (float)sin((double)fr);
  }
  __syncthreads();
  if (tid < 64) {
    const float* kp = kva + (size_t)t * 576 + 512;
    float xv = kp[tid];
    float rh = (tid & 1) ? kp[tid - 1] : -kp[tid + 1];
    kr[tid] = xv * cs[tid] + rh * sn[tid];
  }
  __syncthreads();
  const bf16* qb = q + (size_t)t * 3072;
  const bf16* kvb = kv + (size_t)t * 4096;
  for (int idx = tid; idx < 16 * 192; idx += 256) {
    int hh = idx / 192, d = idx - hh * 192;
    size_t ob = ((size_t)(b * 16 + hh) * 1024 + s) * 192 + d;
    const bf16* qr = qb + hh * 192;
    float qv;
    if (d < 128) qv = (float)qr[d] + (float)qr[qPl + d];
    else {
      int dd = d - 128;
      float xv = (float)qr[128 + dd] + (float)qr[qPl + 128 + dd];
      float rh;
      if (dd & 1) rh = (float)qr[128 + dd - 1] + (float)qr[qPl + 128 + dd - 1];
      else rh = -((float)qr[128 + dd + 1] + (float)qr[qPl + 128 + dd + 1]);
      qv = xv * cs[dd] + rh * sn[dd];
    }
    bf16 qh = cvt(qv);
    qf[ob] = qh;
    qf[fPl + ob] = cvt(qv - (float)qh);
    float kvv;
    if (d < 128) kvv = (float)kvb[hh * 256 + d] + (float)kvb[kvPl + hh * 256 + d];
    else kvv = kr[d - 128];
    bf16 kh = cvt(kvv);
    kf[ob] = kh;
    kf[fPl + ob] = cvt(kvv - (float)kh);
  }
  for (int idx = tid; idx < 16 * 128; idx += 256) {
    int hh = idx >> 7, d = idx & 127;
    size_t ov = ((size_t)(b * 16 + hh) * 1024 + s) * 128 + d;
    float v = (float)kvb[hh * 256 + 128 + d] + (float)kvb[kvPl + hh * 256 + 128 + d];
    bf16 vh = cvt(v);
    vvp[ov] = vh;
    vvp[vPl + ov] = cvt(v - (float)vh);
  }
}

// ---------------- causal flash attention, split-bf16 precision, 64-row Q tiles, 4 waves x 16 rows
__global__ __launch_bounds__(256, 1)
void attn_k(const bf16* __restrict__ qf, const bf16* __restrict__ kf, size_t fPl,
            const bf16* __restrict__ vv, size_t vPl, bf16* __restrict__ ao, size_t aoPl) {
  int qt = blockIdx.x;
  int bh = blockIdx.y;
  int b = bh >> 4, h = bh & 15;
  int tid = threadIdx.x, w = tid >> 6, l = tid & 63;
  size_t base192 = (size_t)bh * 1024 * 192;
  size_t base128 = (size_t)bh * 1024 * 128;

  __shared__ __align__(16) bf16 Kt[2 * 64 * 200];
  __shared__ __align__(16) bf16 Vt[2 * 128 * 72];
  __shared__ __align__(16) bf16 Pt[2][4][16 * 72];

  bf16x8 aqh[6], aql[6];
  {
    const bf16* qp = qf + base192 + (size_t)(qt * 64 + w * 16 + (l & 15)) * 192 + ((l >> 4) << 3);
#pragma unroll
    for (int kc = 0; kc < 6; ++kc) {
      aqh[kc] = *(const bf16x8*)(qp + kc * 32);
      aql[kc] = *(const bf16x8*)(qp + fPl + kc * 32);
    }
  }
  f32x4 o[8];
#pragma unroll
  for (int i = 0; i < 8; ++i) o[i] = (f32x4){0.f, 0.f, 0.f, 0.f};
  float m_[4], s_[4];
#pragma unroll
  for (int j = 0; j < 4; ++j) { m_[j] = -3e38f; s_[j] = 0.f; }
  const float rs = 0.0721687836f;  // 1/sqrt(192)
  int qrow0 = qt * 64 + w * 16 + ((l >> 4) << 2);

  for (int kt = 0; kt <= qt; ++kt) {
    __syncthreads();
#pragma unroll
    for (int p = 0; p < 2; ++p) {
#pragma unroll
      for (int i = 0; i < 6; ++i) {
        int chunk = i * 256 + tid;
        int r = chunk / 24, cc = (chunk - r * 24) * 8;
        *(bf16x8*)&Kt[p * 12800 + r * 200 + cc] =
            *(const bf16x8*)(kf + p * fPl + base192 + (size_t)(kt * 64 + r) * 192 + cc);
      }
#pragma unroll
      for (int i = 0; i < 4; ++i) {
        int chunk = i * 256 + tid;
        int r = chunk >> 4, cc = (chunk & 15) * 8;
        bf16x8 vd = *(const bf16x8*)(vv + p * vPl + base128 + (size_t)(kt * 64 + r) * 128 + cc);
#pragma unroll
        for (int j = 0; j < 8; ++j) Vt[p * 9216 + (cc + j) * 72 + r] = *((const bf16*)&vd + j);
      }
    }
    __syncthreads();

    f32x4 sc[4];
#pragma unroll
    for (int nt = 0; nt < 4; ++nt) {
      sc[nt] = (f32x4){0.f, 0.f, 0.f, 0.f};
#pragma unroll
      for (int kc = 0; kc < 6; ++kc) {
        int ko = (nt * 16 + (l & 15)) * 200 + kc * 32 + ((l >> 4) << 3);
        bf16x8 bkh = *(const bf16x8*)&Kt[ko];
        bf16x8 bkl = *(const bf16x8*)&Kt[12800 + ko];
        sc[nt] = __builtin_amdgcn_mfma_f32_16x16x32_bf16(aqh[kc], bkh, sc[nt], 0, 0, 0);
        sc[nt] = __builtin_amdgcn_mfma_f32_16x16x32_bf16(aql[kc], bkh, sc[nt], 0, 0, 0);
        sc[nt] = __builtin_amdgcn_mfma_f32_16x16x32_bf16(aqh[kc], bkl, sc[nt], 0, 0, 0);
      }
    }
#pragma unroll
    for (int nt = 0; nt < 4; ++nt) {
      int kcol = kt * 64 + nt * 16 + (l & 15);
#pragma unroll
      for (int j = 0; j < 4; ++j) {
        float xv = sc[nt][j] * rs;
        if (kt == qt && kcol > qrow0 + j) xv = -1e30f;
        sc[nt][j] = xv;
      }
    }
#pragma unroll
    for (int j = 0; j < 4; ++j) {
      float mm = fmaxf(fmaxf(sc[0][j], sc[1][j]), fmaxf(sc[2][j], sc[3][j]));
#pragma unroll
      for (int d = 1; d < 16; d <<= 1) mm = fmaxf(mm, __shfl_xor(mm, d, 64));
      float mnew = fmaxf(m_[j], mm);
      float f = __expf(m_[j] - mnew);
      float ps = 0.f;
#pragma unroll
      for (int nt = 0; nt < 4; ++nt) {
        float p = __expf(sc[nt][j] - mnew);
        sc[nt][j] = p;
        ps += p;
      }
#pragma unroll
      for (int d = 1; d < 16; d <<= 1) ps += __shfl_xor(ps, d, 64);
      s_[j] = s_[j] * f + ps;
      m_[j] = mnew;
#pragma unroll
      for (int nt = 0; nt < 8; ++nt) o[nt][j] *= f;
    }
#pragma unroll
    for (int nt = 0; nt < 4; ++nt)
#pragma unroll
      for (int j = 0; j < 4; ++j) {
        float p = sc[nt][j];
        bf16 ph = cvt(p);
        int po = (((l >> 4) << 2) + j) * 72 + nt * 16 + (l & 15);
        Pt[0][w][po] = ph;
        Pt[1][w][po] = cvt(p - (float)ph);
      }
#pragma unroll
    for (int kc = 0; kc < 2; ++kc) {
      int pofs = (l & 15) * 72 + kc * 32 + ((l >> 4) << 3);
      bf16x8 aph = *(const bf16x8*)&Pt[0][w][pofs];
      bf16x8 apl = *(const bf16x8*)&Pt[1][w][pofs];
#pragma unroll
      for (int nt = 0; nt < 8; ++nt) {
        int vo = (nt * 16 + (l & 15)) * 72 + kc * 32 + ((l >> 4) << 3);
        bf16x8 bvh = *(const bf16x8*)&Vt[vo];
        bf16x8 bvl = *(const bf16x8*)&Vt[9216 + vo];
        o[nt] = __builtin_amdgcn_mfma_f32_16x16x32_bf16(aph, bvh, o[nt], 0, 0, 0);
        o[nt] = __builtin_amdgcn_mfma_f32_16x16x32_bf16(apl, bvh, o[nt], 0, 0, 0);
        o[nt] = __builtin_amdgcn_mfma_f32_16x16x32_bf16(aph, bvl, o[nt], 0, 0, 0);
      }
    }
  }
#pragma unroll
  for (int nt = 0; nt < 8; ++nt)
#pragma unroll
    for (int j = 0; j < 4; ++j) {
      size_t trow = (size_t)(b * 1024 + qrow0 + j);
      float v = o[nt][j] / s_[j];
      bf16 vh = cvt(v);
      size_t oi = trow * 2048 + h * 128 + nt * 16 + (l & 15);
      ao[oi] = vh;
      ao[aoPl + oi] = cvt(v - (float)vh);
    }
}

// ---------------- routing from fp32 h (re-does norm2 in fp32 so top-k decisions match reference)
__global__ __launch_bounds__(256) void route1(const float* __restrict__ h, const float* __restrict__ n2w,
                                              const float* __restrict__ gw, const float* __restrict__ gbias,
                                              float* __restrict__ wcomb, int* __restrict__ gmask,
                                              int* __restrict__ cnt) {
  int t = blockIdx.x;
  int tid = threadIdx.x, w = tid >> 6, l = tid & 63;
  const float* hp = h + (size_t)t * 2048;
  __shared__ float xr[2048];
  __shared__ float part[4];
  __shared__ float scs[16];
  float ss = 0.f;
  for (int i = tid; i < 512; i += 256) {
    float4 v = ((const float4*)hp)[i];
    ss += v.x * v.x + v.y * v.y + v.z * v.z + v.w * v.w;
  }
#pragma unroll
  for (int d = 1; d < 64; d <<= 1) ss += __shfl_xor(ss, d, 64);
  if (l == 0) part[w] = ss;
  __syncthreads();
  float rinv = rsqrtf((part[0] + part[1] + part[2] + part[3]) / 2048.f + 1e-6f);
  for (int i = tid; i < 512; i += 256) {
    float4 v = ((const float4*)hp)[i];
    float4 g = ((const float4*)n2w)[i];
    xr[i * 4 + 0] = v.x * rinv * g.x;
    xr[i * 4 + 1] = v.y * rinv * g.y;
    xr[i * 4 + 2] = v.z * rinv * g.z;
    xr[i * 4 + 3] = v.w * rinv * g.w;
  }
  __syncthreads();
#pragma unroll
  for (int ee = 0; ee < 4; ++ee) {
    int e = w * 4 + ee;
    float s = 0.f;
    for (int k = l; k < 2048; k += 64) s += xr[k] * gw[e * 2048 + k];
#pragma unroll
    for (int d = 1; d < 64; d <<= 1) s += __shfl_xor(s, d, 64);
    if (l == 0) scs[e] = 1.f / (1.f + expf(-s));
  }
  __syncthreads();
  if (tid == 0) {
    float scb[16];
#pragma unroll
    for (int e2 = 0; e2 < 16; ++e2) scb[e2] = scs[e2] + gbias[e2];
    float gsc[8];
#pragma unroll
    for (int g = 0; g < 8; ++g) gsc[g] = scb[2 * g] + scb[2 * g + 1];
    int mask = 0;
    for (int it = 0; it < 4; ++it) {
      float best = -3e38f;
      int bg = 0;
      for (int g = 0; g < 8; ++g)
        if (!((mask >> g) & 1) && gsc[g] > best) { best = gsc[g]; bg = g; }
      mask |= 1 << bg;
    }
    float wv[16];
#pragma unroll
    for (int e2 = 0; e2 < 16; ++e2) wv[e2] = 0.f;
    float wsum = 0.f;
    for (int g = 0; g < 8; ++g)
      if ((mask >> g) & 1) {
        wv[2 * g] = scs[2 * g];
        wv[2 * g + 1] = scs[2 * g + 1];
        wsum += scs[2 * g] + scs[2 * g + 1];
        atomicAdd(&cnt[2 * g], 1);
        atomicAdd(&cnt[2 * g + 1], 1);
      }
    float inv = 2.5f / (wsum + 1e-20f);
#pragma unroll
    for (int e2 = 0; e2 < 16; ++e2) wcomb[t * 16 + e2] = wv[e2] * inv;
    gmask[t] = mask;
  }
}

__global__ void route2(const int* __restrict__ cnt, int* __restrict__ offs) {
  if (threadIdx.x == 0) {
    int a = 0;
    for (int e = 0; e < 16; ++e) { offs[e] = a; a += cnt[e]; }
  }
}

__global__ void route3(const float* __restrict__ wcomb, const int* __restrict__ gmask,
                       const int* __restrict__ offs, int* __restrict__ fill,
                       int* __restrict__ tok_of, float* __restrict__ w_of, int* __restrict__ slot_of) {
  int t = blockIdx.x * 256 + threadIdx.x;
  if (t >= TT) return;
  int mask = gmask[t];
  int j = 0;
  for (int g = 0; g < 8; ++g) {
    if (!((mask >> g) & 1)) continue;
    for (int p = 0; p < 2; ++p) {
      int e = 2 * g + p;
      int pos = atomicAdd(&fill[e], 1);
      int slot = offs[e] + pos;
      tok_of[slot] = t;
      w_of[slot] = wcomb[t * 16 + e];
      slot_of[t * 8 + j] = slot;
      ++j;
    }
  }
}

// ---------------- final: out[t] += sum of 8 pre-weighted expert rows (out already = h + shared)
__global__ __launch_bounds__(256) void finalk(const bf16* __restrict__ eo,
                                              const int* __restrict__ slot_of, float* __restrict__ out) {
  int t = blockIdx.x, tid = threadIdx.x;
  float* op = out + (size_t)t * 2048;
  float a[8];
  float4 h0 = ((const float4*)op)[tid * 2];
  float4 h1v = ((const float4*)op)[tid * 2 + 1];
  a[0] = h0.x; a[1] = h0.y; a[2] = h0.z; a[3] = h0.w;
  a[4] = h1v.x; a[5] = h1v.y; a[6] = h1v.z; a[7] = h1v.w;
#pragma unroll
  for (int j = 0; j < 8; ++j) {
    int slot = slot_of[t * 8 + j];
    bf16x8 v = ((const bf16x8*)(eo + (size_t)slot * 2048))[tid];
#pragma unroll
    for (int i = 0; i < 8; ++i) a[i] += (float)v[i];
  }
  ((float4*)op)[tid * 2] = make_float4(a[0], a[1], a[2], a[3]);
  ((float4*)op)[tid * 2 + 1] = make_float4(a[4], a[5], a[6], a[7]);
}

extern "C" void kernel_launch(void* const* d_in, const int* in_sizes, int n_in,
                              void* d_out, int out_size, void* d_ws, size_t ws_size,
                              hipStream_t stream) {
  (void)in_sizes; (void)n_in; (void)out_size; (void)ws_size;
  const float* x        = (const float*)d_in[0];
  const float* norm1_w  = (const float*)d_in[1];
  const float* w_q_a    = (const float*)d_in[2];
  const float* q_a_norm = (const float*)d_in[3];
  const float* w_q_b    = (const float*)d_in[4];
  const float* w_kv_a   = (const float*)d_in[5];
  const float* kv_a_norm= (const float*)d_in[6];
  const float* w_kv_b   = (const float*)d_in[7];
  const float* w_out    = (const float*)d_in[8];
  const float* norm2_w  = (const float*)d_in[9];
  const float* gate_w   = (const float*)d_in[10];
  const float* gate_b   = (const float*)d_in[11];
  const float* w_gate   = (const float*)d_in[12];
  const float* w_up     = (const float*)d_in[13];
  const float* w_down   = (const float*)d_in[14];
  const float* ws_gate  = (const float*)d_in[15];
  const float* ws_up    = (const float*)d_in[16];
  const float* ws_down  = (const float*)d_in[17];
  float* out = (float*)d_out;   // doubles as the fp32 residual h
  char* ws = (char*)d_ws;

  size_t cur = 0;
  auto al = [&](size_t b) { size_t o = cur; cur = (cur + b + 255) & ~(size_t)255; return o; };

  // --- dedicated (never overlaid) routing metadata
  size_t o_wcomb= al((size_t)TT * 16 * 4);
  size_t o_gmask= al((size_t)TT * 4);
  size_t o_cnt  = al(256);
  size_t o_fill = al(256);
  size_t o_offs = al(256);
  size_t o_tok  = al((size_t)(NSLOT + 128) * 4);
  size_t o_wof  = al((size_t)(NSLOT + 128) * 4);
  size_t o_slot = al((size_t)TT * 8 * 4);

  // --- big union region R1
  size_t r1 = cur;
  // phase1 (attention path; dead after attention / w_out gemm)
  size_t o_qlat = al((size_t)TT * 512 * 4);        // fp32
  size_t o_kva  = al((size_t)TT * 576 * 4);        // fp32 (lives until rope_pack)
  size_t o_qn   = al((size_t)TT * 512 * 2 * 2);    // hi/lo
  size_t o_kvn  = al((size_t)TT * 512 * 2 * 2);
  size_t o_qbig = al((size_t)TT * 3072 * 2 * 2);
  size_t o_kvbig= al((size_t)TT * 4096 * 2 * 2);
  size_t o_qf   = al((size_t)TT * 3072 * 2 * 2);
  size_t o_kf   = al((size_t)TT * 3072 * 2 * 2);
  size_t o_vv   = al((size_t)TT * 2048 * 2 * 2);
  size_t r1end = cur;
  // phase2 (MoE; all launches after attention). Reuse trick:
  //  - ffn_act reads Wg,Wu -> then w_down is transposed into the (dead) Wg slot
  //  - eo exactly occupies the (dead) Wu+Wd slots (33.55MB + 33.55MB = 67.1MB = NSLOT*2048*2)
  cur = r1;
  size_t o_Wg  = al((size_t)16 * 512 * 2048 * 2);   // later: Wd2 (transposed w_down)
  size_t o_Wu  = al((size_t)16 * 512 * 2048 * 2);   // later: eo (spans Wu+Wd slots)
  size_t o_Wd  = al((size_t)16 * 2048 * 512 * 2);
  size_t o_act  = al((size_t)(NSLOT + 128) * 512 * 2);
  size_t o_acts = al((size_t)TT * 512 * 2);
  if (cur < r1end) cur = r1end;
  size_t o_Wd2 = o_Wg;  // w_down transposed (after ffn_act done with Wg)
  size_t o_eo  = o_Wu;  // expert outputs (after ffn_act done with Wu; spans Wu+Wd)

  size_t o_h1 = al((size_t)TT * 2048 * 2 * 2);  // h1 hi/lo; reused as ao hi/lo after it dies
  size_t o_ao = o_h1;
  size_t o_xt = al((size_t)TT * 2048 * 2);
  size_t o_scr = al((size_t)2048 * 2048 * 2 * 2);  // transposed-weight scratch (max: w_out split)
  size_t o_scr2 = o_scr + (size_t)512 * 2048 * 2;  // second plain slot (ws_up)

  auto W = [&](size_t o) { return (bf16*)(ws + o); };
  auto F = [&](size_t o) { return (float*)(ws + o); };
  auto I = [&](size_t o) { return (int*)(ws + o); };

  // plane offsets (elements)
  const size_t PLh1 = (size_t)TT * 2048, PLqn = (size_t)TT * 512, PLqb = (size_t)TT * 3072,
               PLkvb = (size_t)TT * 4096, PLf = (size_t)TT * 3072, PLv = (size_t)TT * 2048,
               PLao = (size_t)TT * 2048;
  const size_t PLwqa = (size_t)512 * 2048, PLwkva = (size_t)640 * 2048, PLwqb = (size_t)3072 * 512,
               PLwkvb = (size_t)4096 * 512, PLwout = (size_t)2048 * 2048;

  hipMemsetAsync(ws + o_cnt, 0, 512, stream);  // cnt + fill

  rms_k<true><<<TT, 256, 0, stream>>>(x, 2048, 2048, norm1_w, W(o_h1), PLh1);

  // q_a / kv_a projections (split precision, fp32 out)
  transpose_cvt<true><<<dim3(16, 64, 1), 256, 0, stream>>>(w_q_a, W(o_scr), 2048, 512, 512);
  gemm128<E_F32, false, true><<<dim3(16, 4), 256, 0, stream>>>(W(o_h1), 2048, PLh1, W(o_scr), PLwqa, 0, 2048, F(o_qlat), 0, nullptr, TT, 512, 512, nullptr, nullptr, nullptr);
  transpose_cvt<true><<<dim3(20, 64, 1), 256, 0, stream>>>(w_kv_a, W(o_scr), 2048, 576, 640);
  gemm128<E_F32, false, true><<<dim3(16, 5), 256, 0, stream>>>(W(o_h1), 2048, PLh1, W(o_scr), PLwkva, 0, 2048, F(o_kva), 0, nullptr, TT, 576, 576, nullptr, nullptr, nullptr);

  rms_k<true><<<TT, 256, 0, stream>>>(F(o_qlat), 512, 512, q_a_norm, W(o_qn), PLqn);
  rms_k<true><<<TT, 256, 0, stream>>>(F(o_kva), 576, 512, kv_a_norm, W(o_kvn), PLqn);

  // q_b / kv_b projections (split in, split out)
  transpose_cvt<true><<<dim3(96, 16, 1), 256, 0, stream>>>(w_q_b, W(o_scr), 512, 3072, 3072);
  gemm128<E_SPLIT, false, true><<<dim3(16, 24), 256, 0, stream>>>(W(o_qn), 512, PLqn, W(o_scr), PLwqb, 0, 512, W(o_qbig), PLqb, nullptr, TT, 3072, 3072, nullptr, nullptr, nullptr);
  transpose_cvt<true><<<dim3(128, 16, 1), 256, 0, stream>>>(w_kv_b, W(o_scr), 512, 4096, 4096);
  gemm128<E_SPLIT, false, true><<<dim3(16, 32), 256, 0, stream>>>(W(o_kvn), 512, PLqn, W(o_scr), PLwkvb, 0, 512, W(o_kvbig), PLkvb, nullptr, TT, 4096, 4096, nullptr, nullptr, nullptr);

  rope_pack<<<TT, 256, 0, stream>>>(W(o_qbig), PLqb, W(o_kvbig), PLkvb, F(o_kva), W(o_qf), W(o_kf), PLf, W(o_vv), PLv);

  attn_k<<<dim3(16, 32), 256, 0, stream>>>(W(o_qf), W(o_kf), PLf, W(o_vv), PLv, W(o_ao), PLao);

  // out = ao @ w_out + x   (split precision; out doubles as residual h)
  transpose_cvt<true><<<dim3(64, 64, 1), 256, 0, stream>>>(w_out, W(o_scr), 2048, 2048, 2048);
  gemm128<E_ADDSRC, false, true><<<dim3(16, 16), 256, 0, stream>>>(W(o_ao), 2048, PLao, W(o_scr), PLwout, 0, 2048, out, 0, x, TT, 2048, 2048, nullptr, nullptr, nullptr);

  rms_k<false><<<TT, 256, 0, stream>>>(out, 2048, 2048, norm2_w, W(o_xt), 0);

  route1<<<TT, 256, 0, stream>>>(out, norm2_w, gate_w, gate_b, F(o_wcomb), I(o_gmask), I(o_cnt));
  route2<<<1, 64, 0, stream>>>(I(o_cnt), I(o_offs));
  route3<<<TT / 256, 256, 0, stream>>>(F(o_wcomb), I(o_gmask), I(o_offs), I(o_fill), I(o_tok), F(o_wof), I(o_slot));

  // shared FFN (plain bf16): acts = silu(xt@ws_gate)*(xt@ws_up); out += acts @ ws_down
  transpose_cvt<false><<<dim3(16, 64, 1), 256, 0, stream>>>(ws_gate, W(o_scr), 2048, 512, 512);
  transpose_cvt<false><<<dim3(16, 64, 1), 256, 0, stream>>>(ws_up, W(o_scr2), 2048, 512, 512);
  ffn_act<false><<<dim3(16, 8, 1), 256, 0, stream>>>(W(o_xt), W(o_scr), W(o_scr2), 0, W(o_acts), nullptr, nullptr, nullptr, TT);
  transpose_cvt<false><<<dim3(64, 16, 1), 256, 0, stream>>>(ws_down, W(o_scr), 512, 2048, 2048);
  gemm128<E_ADDINTO, false, false><<<dim3(16, 16), 256, 0, stream>>>(W(o_acts), 512, 0, W(o_scr), 0, 0, 512, out, 0, nullptr, TT, 2048, 2048, nullptr, nullptr, nullptr);

  // expert FFN (grouped, plain bf16): act = silu(g)*u; eo[slot] = (act @ w_down[e]) * w_slot
  // grids ordered (n_tiles, E, m_tiles) so early-exit m dimension is slowest (anti-clustering)
  transpose_cvt<false><<<dim3(16, 64, 16), 256, 0, stream>>>(w_gate, W(o_Wg), 2048, 512, 512);
  transpose_cvt<false><<<dim3(16, 64, 16), 256, 0, stream>>>(w_up, W(o_Wu), 2048, 512, 512);
  ffn_act<true><<<dim3(8, 16, 32), 256, 0, stream>>>(W(o_xt), W(o_Wg), W(o_Wu), (size_t)512 * 2048, W(o_act), I(o_cnt), I(o_offs), I(o_tok), 0);
  transpose_cvt<false><<<dim3(64, 16, 16), 256, 0, stream>>>(w_down, W(o_Wd2), 512, 2048, 2048);
  gemm128<E_BF16SC, true, false><<<dim3(16, 16, 32), 256, 0, stream>>>(W(o_act), 512, 0, W(o_Wd2), 0, (size_t)2048 * 512, 512, W(o_eo), 0, nullptr, 0, 2048, 2048, I(o_cnt), I(o_offs), F(o_wof));

  // out[t] += sum of this token's 8 expert rows
  finalk<<<TT, 256, 0, stream>>>(W(o_eo), I(o_slot), out);
}